// Round 10
// baseline (417.945 us; speedup 1.0000x reference)
//
#include <hip/hip_runtime.h>
#include <stdint.h>

#define H_B  4
#define H_SQ 1024
#define H_SK 2048
#define H_D  1024
#define H_NH 16
#define H_DH 64

typedef __bf16 bf16x8 __attribute__((ext_vector_type(8)));
typedef float  f32x4  __attribute__((ext_vector_type(4)));

__device__ __forceinline__ uint16_t f2bf(float f) {
    union { float f; uint32_t u; } v; v.f = f;
    uint32_t r = v.u + 0x7fffu + ((v.u >> 16) & 1u);
    return (uint16_t)(r >> 16);
}

__device__ __forceinline__ void gload_lds16(const void* g, void* l) {
    __builtin_amdgcn_global_load_lds(
        (const __attribute__((address_space(1))) uint32_t*)g,
        (__attribute__((address_space(3))) uint32_t*)l, 16, 0, 0);
}

#define MFMA_BF16(a, b, c) __builtin_amdgcn_mfma_f32_16x16x32_bf16((a), (b), (c), 0, 0, 0)
#define EXP2(x) __builtin_amdgcn_exp2f(x)

// DPP crosslane (VALU pipe — not DS): xor within 16-lane row groups
template <int CTRL>
__device__ __forceinline__ float dpp_xor(float v) {
    return __builtin_bit_cast(float,
        __builtin_amdgcn_update_dpp(__builtin_bit_cast(int, v),
                                    __builtin_bit_cast(int, v),
                                    CTRL, 0xF, 0xF, false));
}
#define DPP_XOR1 0xB1   // quad_perm(1,0,3,2)
#define DPP_XOR2 0x4E   // quad_perm(2,3,0,1)
#define DPP_XOR4 0x141  // row_half_mirror
#define DPP_XOR8 0x140  // row_mirror

__device__ __forceinline__ float dpp_max16(float v) {
    v = fmaxf(v, dpp_xor<DPP_XOR1>(v));
    v = fmaxf(v, dpp_xor<DPP_XOR2>(v));
    v = fmaxf(v, dpp_xor<DPP_XOR4>(v));
    v = fmaxf(v, dpp_xor<DPP_XOR8>(v));
    return v;
}
__device__ __forceinline__ float dpp_sum16(float v) {
    v += dpp_xor<DPP_XOR1>(v);
    v += dpp_xor<DPP_XOR2>(v);
    v += dpp_xor<DPP_XOR4>(v);
    v += dpp_xor<DPP_XOR8>(v);
    return v;
}

// ---------------- f32 -> bf16 convert (vectorized, grid-stride) ----------------
__global__ void cvt_bf16_kernel(const float* __restrict__ in, uint16_t* __restrict__ out, int n4) {
    int i = blockIdx.x * blockDim.x + threadIdx.x;
    int stride = gridDim.x * blockDim.x;
    for (; i < n4; i += stride) {
        float4 v = ((const float4*)in)[i];
        ushort4 o;
        o.x = f2bf(v.x); o.y = f2bf(v.y); o.z = f2bf(v.z); o.w = f2bf(v.w);
        ((ushort4*)out)[i] = o;
    }
}

// ---------------- weight transpose + convert: W[K][N] f32 -> WT[N][K] bf16 ------
__global__ void wtrans_kernel(const float* __restrict__ W, uint16_t* __restrict__ WT, int K, int N) {
    __shared__ float tile[32][33];
    int n0 = blockIdx.x * 32, k0 = blockIdx.y * 32;
    int tx = threadIdx.x, ty = threadIdx.y;           // block (32,8)
    #pragma unroll
    for (int i = ty; i < 32; i += 8)
        tile[i][tx] = W[(size_t)(k0 + i) * N + n0 + tx];
    __syncthreads();
    #pragma unroll
    for (int i = ty; i < 32; i += 8)
        WT[(size_t)(n0 + i) * K + k0 + tx] = f2bf(tile[tx][i]);
}

// ---------------- GEMM: C[M][N] = A[M][K] @ BT[N][K]^T + bias, bf16 in ----------
// 2-phase double-buffered LDS. MODE 0: bf16 C. MODE 1: f32 C.
// MODE 2 (kv projection): cols < H_D -> kb[row][col] (stride H_D, K-half);
//                         cols >= H_D -> vT[(b*16+hh)*64+dd][sk] transposed,
//                         packed 4 sk per uint2 store. Fuses the old vtrans.
template <int MODE>
__global__ __launch_bounds__(256) void gemm_bt_kernel(
    const uint16_t* __restrict__ A, const uint16_t* __restrict__ BT,
    const float* __restrict__ bias, void* __restrict__ Cv,
    uint16_t* __restrict__ vTb, int M, int N, int K)
{
    __shared__ uint16_t As[2][128 * 32];
    __shared__ uint16_t Bs[2][128 * 32];

    int nbn = N >> 7;
    int nwg = gridDim.x;
    int cpx = nwg >> 3;                         // nwg divisible by 8 for all our shapes
    int wg = blockIdx.x;
    wg = (wg & 7) * cpx + (wg >> 3);            // XCD-aware swizzle (bijective)
    int bm = wg / nbn, bn = wg % nbn;

    int t = threadIdx.x;
    int w = t >> 6, l = t & 63;
    int lr = l & 15, lg = l >> 4;
    int wr = (w >> 1) * 64, wc = (w & 1) * 64;

    const uint16_t* Ab = A + (size_t)bm * 128 * K;
    const uint16_t* Bb = BT + (size_t)bn * 128 * K;

    // per-thread staging chunk geometry: chunk c -> row c>>2, 16B piece c&3
    int ca = w * 64 + l;
    int rowa = ca >> 2, kpa = (ca & 3) * 8;
    int cb = 256 + ca;
    int rowb = cb >> 2, kpb = (cb & 3) * 8;
    int offa = ca * 16;          // linear LDS byte offsets (dest = base + lane*16)
    int offb = cb * 16;

    f32x4 acc[4][4];
    #pragma unroll
    for (int i = 0; i < 4; ++i)
        #pragma unroll
        for (int j = 0; j < 4; ++j) acc[i][j] = {0.f, 0.f, 0.f, 0.f};

    // prologue: stage k0 = 0 into buffer 0
    gload_lds16(Ab + (size_t)rowa * K + kpa, (char*)As[0] + (offa & ~1023));
    gload_lds16(Ab + (size_t)rowb * K + kpb, (char*)As[0] + (offb & ~1023));
    gload_lds16(Bb + (size_t)rowa * K + kpa, (char*)Bs[0] + (offa & ~1023));
    gload_lds16(Bb + (size_t)rowb * K + kpb, (char*)Bs[0] + (offb & ~1023));
    __syncthreads();

    int buf = 0;
    for (int k0 = 0; k0 < K; k0 += 32) {
        if (k0 + 32 < K) {               // stage next K-tile into other buffer
            int kn = k0 + 32;
            gload_lds16(Ab + (size_t)rowa * K + kn + kpa, (char*)As[buf ^ 1] + (offa & ~1023));
            gload_lds16(Ab + (size_t)rowb * K + kn + kpb, (char*)As[buf ^ 1] + (offb & ~1023));
            gload_lds16(Bb + (size_t)rowa * K + kn + kpa, (char*)Bs[buf ^ 1] + (offa & ~1023));
            gload_lds16(Bb + (size_t)rowb * K + kn + kpb, (char*)Bs[buf ^ 1] + (offb & ~1023));
        }
        bf16x8 af[4], bf[4];
        #pragma unroll
        for (int mi = 0; mi < 4; ++mi)
            af[mi] = *(const bf16x8*)&As[buf][(wr + mi * 16 + lr) * 32 + lg * 8];
        #pragma unroll
        for (int ni = 0; ni < 4; ++ni)
            bf[ni] = *(const bf16x8*)&Bs[buf][(wc + ni * 16 + lr) * 32 + lg * 8];
        #pragma unroll
        for (int mi = 0; mi < 4; ++mi)
            #pragma unroll
            for (int ni = 0; ni < 4; ++ni)
                acc[mi][ni] = MFMA_BF16(af[mi], bf[ni], acc[mi][ni]);
        __syncthreads();                 // drains staging vmcnt + read handoff
        buf ^= 1;
    }

    #pragma unroll
    for (int mi = 0; mi < 4; ++mi) {
        #pragma unroll
        for (int ni = 0; ni < 4; ++ni) {
            int col = bn * 128 + wc + ni * 16 + lr;
            float bv = bias[col];
            int row0 = bm * 128 + wr + mi * 16 + lg * 4;
            if constexpr (MODE == 2) {
                if (col < H_D) {         // K-half -> kb[row][col], stride H_D
                    uint16_t* kb = (uint16_t*)Cv;
                    #pragma unroll
                    for (int j = 0; j < 4; ++j)
                        kb[(size_t)(row0 + j) * H_D + col] = f2bf(acc[mi][ni][j] + bv);
                } else {                 // V-half -> vT[(b*16+hh)*64+dd][sk], packed
                    int dall = col - H_D;
                    int hh = dall >> 6, dd = dall & 63;
                    int bb = row0 >> 11, sk0 = row0 & 2047;  // 128-tiles don't cross b
                    uint16_t p0 = f2bf(acc[mi][ni][0] + bv);
                    uint16_t p1 = f2bf(acc[mi][ni][1] + bv);
                    uint16_t p2 = f2bf(acc[mi][ni][2] + bv);
                    uint16_t p3 = f2bf(acc[mi][ni][3] + bv);
                    uint32_t lo = (uint32_t)p0 | ((uint32_t)p1 << 16);
                    uint32_t hi = (uint32_t)p2 | ((uint32_t)p3 << 16);
                    *(uint2*)&vTb[((size_t)(bb * 16 + hh) * 64 + dd) * H_SK + sk0] =
                        make_uint2(lo, hi);
                }
            } else {
                #pragma unroll
                for (int j = 0; j < 4; ++j) {
                    float v = acc[mi][ni][j] + bv;
                    if constexpr (MODE == 0)
                        ((uint16_t*)Cv)[(size_t)(row0 + j) * N + col] = f2bf(v);
                    else
                        ((float*)Cv)[(size_t)(row0 + j) * N + col] = v;
                }
            }
        }
    }
}

// ---------------- flash attention (r9 math, NO K/V LDS staging) -----------------
// Panels are L2-resident (panel swizzle pins all 16 q-tiles of one (b,h) to one
// XCD), so K/V fragments are read DIRECTLY from global (L2 hit) — no staging,
// no double-buffer, no barriers (p_lds is wave-private). LDS = 8.7KB -> waves
// fully independent; latency hidden by TLP instead of a staging pipeline.
__global__ __launch_bounds__(256) void attn_kernel(
    const uint16_t* __restrict__ qb, const uint16_t* __restrict__ kb,
    const uint16_t* __restrict__ vT, const float* __restrict__ mask,
    uint16_t* __restrict__ ab)
{
    __shared__ uint16_t p_lds[4][16][68]; // stride 68: b16 writes spread all banks

    int bid = blockIdx.x;
    int xcd = bid & 7;
    int kk = bid >> 3;               // 0..127
    int qt = kk & 15;
    int bh = xcd + 8 * (kk >> 4);    // bijective; panel blocks share bid%8
    int b = bh >> 4, hh = bh & 15;

    int t = threadIdx.x;
    int w = t >> 6, l = t & 63;
    int lr = l & 15, lg = l >> 4;

    // Q fragments straight from global (once per block)
    const uint16_t* qrow = qb + (size_t)(b * H_SQ + qt * 64 + w * 16 + lr) * H_D + hh * H_DH;
    bf16x8 qf0 = *(const bf16x8*)(qrow + lg * 8);
    bf16x8 qf1 = *(const bf16x8*)(qrow + 32 + lg * 8);

    f32x4 acc[4];
    #pragma unroll
    for (int i = 0; i < 4; ++i) acc[i] = {0.f, 0.f, 0.f, 0.f};
    float mrow[4], lsum[4];   // lsum = per-lane PARTIAL (this lane's ni columns)
    #pragma unroll
    for (int j = 0; j < 4; ++j) { mrow[j] = -1e30f; lsum[j] = 0.f; }

    const float SC  = 0.18033688011112042f;   // log2(e)/8
    const float L2E = 1.4426950408889634f;

    const uint16_t* kbase = kb + (size_t)b * H_SK * H_D + hh * H_DH;
    const uint16_t* vbase = vT + (size_t)bh * H_DH * H_SK;

    // preload mask(0) premultiplied by log2(e)
    float msk_nxt[4];
    #pragma unroll
    for (int ni = 0; ni < 4; ++ni) msk_nxt[ni] = mask[b * H_SK + ni * 16 + lr] * L2E;

    for (int kt = 0; kt < H_SK / 64; ++kt) {
        int sk0 = kt * 64;
        float msk_cur[4];
        #pragma unroll
        for (int ni = 0; ni < 4; ++ni) msk_cur[ni] = msk_nxt[ni];
        if (kt + 1 < H_SK / 64) {
            #pragma unroll
            for (int ni = 0; ni < 4; ++ni)
                msk_nxt[ni] = mask[b * H_SK + (kt + 1) * 64 + ni * 16 + lr] * L2E;
        }

        // S = Q K^T — K fragments direct from global (L2-hit)
        f32x4 s[4];
        #pragma unroll
        for (int ni = 0; ni < 4; ++ni) s[ni] = {0.f, 0.f, 0.f, 0.f};
        #pragma unroll
        for (int ni = 0; ni < 4; ++ni) {
            const uint16_t* kp = kbase + (size_t)(sk0 + ni * 16 + lr) * H_D;
            bf16x8 kf0 = *(const bf16x8*)(kp + lg * 8);
            bf16x8 kf1 = *(const bf16x8*)(kp + 32 + lg * 8);
            s[ni] = MFMA_BF16(qf0, kf0, s[ni]);
            s[ni] = MFMA_BF16(qf1, kf1, s[ni]);
        }

        // V fragments (independent of softmax) — issue early so L2 latency
        // overlaps the softmax VALU work
        bf16x8 vf0[4], vf1[4];
        #pragma unroll
        for (int ni = 0; ni < 4; ++ni) {
            const uint16_t* vp = vbase + (size_t)(ni * 16 + lr) * H_SK + sk0;
            vf0[ni] = *(const bf16x8*)(vp + lg * 8);
            vf1[ni] = *(const bf16x8*)(vp + 32 + lg * 8);
        }

        // online softmax, exp2 domain; row max via DPP (VALU pipe, no DS)
        float lg2[4][4], mx[4];
        #pragma unroll
        for (int j = 0; j < 4; ++j) {
            float a0 = fmaf(s[0][j], SC, msk_cur[0]);
            float a1 = fmaf(s[1][j], SC, msk_cur[1]);
            float a2 = fmaf(s[2][j], SC, msk_cur[2]);
            float a3 = fmaf(s[3][j], SC, msk_cur[3]);
            lg2[0][j] = a0; lg2[1][j] = a1; lg2[2][j] = a2; lg2[3][j] = a3;
            mx[j] = dpp_max16(fmaxf(fmaxf(a0, a1), fmaxf(a2, a3)));
        }
        // defer-max: only rescale when some row grew past THR=8 (exp2 domain,
        // so P bounded by 2^8=256; f32 lsum/acc have headroom)
        int grow = 0;
        float nm[4];
        #pragma unroll
        for (int j = 0; j < 4; ++j) {
            nm[j] = fmaxf(mrow[j], mx[j]);
            grow |= (mx[j] > mrow[j] + 8.0f) ? 1 : 0;
        }
        if (__any(grow)) {
            #pragma unroll
            for (int j = 0; j < 4; ++j) {
                float alpha = EXP2(mrow[j] - nm[j]);
                mrow[j] = nm[j];
                lsum[j] *= alpha;          // partial: linear in alpha, stays valid
                #pragma unroll
                for (int ni = 0; ni < 4; ++ni) acc[ni][j] *= alpha;
            }
        }
        #pragma unroll
        for (int ni = 0; ni < 4; ++ni)
            #pragma unroll
            for (int j = 0; j < 4; ++j) {
                float p = EXP2(lg2[ni][j] - mrow[j]);
                lsum[j] += p;              // per-lane partial; no cross-lane here
                uint32_t pk;
                asm("v_cvt_pk_bf16_f32 %0, %1, %2" : "=v"(pk) : "v"(p), "v"(p));
                p_lds[w][lg * 4 + j][ni * 16 + lr] = (uint16_t)pk;
            }

        // O += P V  (p_lds wave-private; compiler inserts lgkm waits)
        bf16x8 pf0 = *(const bf16x8*)&p_lds[w][lr][lg * 8];
        bf16x8 pf1 = *(const bf16x8*)&p_lds[w][lr][32 + lg * 8];
        #pragma unroll
        for (int ni = 0; ni < 4; ++ni) {
            acc[ni] = MFMA_BF16(pf0, vf0[ni], acc[ni]);
            acc[ni] = MFMA_BF16(pf1, vf1[ni], acc[ni]);
        }
    }

    // single cross-lane sum reduce at the end (16-lane row groups)
    float inv[4];
    #pragma unroll
    for (int j = 0; j < 4; ++j) inv[j] = 1.0f / dpp_sum16(lsum[j]);
    #pragma unroll
    for (int ni = 0; ni < 4; ++ni)
        #pragma unroll
        for (int j = 0; j < 4; ++j) {
            int row = qt * 64 + w * 16 + lg * 4 + j;
            int col = hh * H_DH + ni * 16 + lr;
            ab[(size_t)(b * H_SQ + row) * H_D + col] = f2bf(acc[ni][j] * inv[j]);
        }
}

// ---------------- host ----------------------------------------------------------
extern "C" void kernel_launch(void* const* d_in, const int* in_sizes, int n_in,
                              void* d_out, int out_size, void* d_ws, size_t ws_size,
                              hipStream_t stream) {
    const float* x    = (const float*)d_in[0];
    const float* ctx  = (const float*)d_in[1];
    const float* mask = (const float*)d_in[2];
    const float* Wq   = (const float*)d_in[3];
    const float* bq   = (const float*)d_in[4];
    const float* Wkv  = (const float*)d_in[5];
    const float* bkv  = (const float*)d_in[6];
    const float* Wp   = (const float*)d_in[7];
    const float* bp   = (const float*)d_in[8];
    float* out = (float*)d_out;

    char* ws = (char*)d_ws;
    uint16_t* xb   = (uint16_t*)(ws + 0);          //  8MB (reused as ab after q GEMM)
    uint16_t* ctxb = (uint16_t*)(ws + 8388608);    // 16MB
    uint16_t* vTb  = (uint16_t*)(ws + 25165824);   // 16MB (written BY kv GEMM -> no alias with ctxb)
    uint16_t* WqT  = (uint16_t*)(ws + 41943040);   //  2MB
    uint16_t* WkvT = (uint16_t*)(ws + 44040192);   //  4MB
    uint16_t* WpT  = (uint16_t*)(ws + 48234496);   //  2MB
    uint16_t* qb   = (uint16_t*)(ws + 50331648);   //  8MB
    uint16_t* kb   = (uint16_t*)(ws + 58720256);   // 16MB -> total 72MB
    uint16_t* ab   = xb;                            // alias: xb dead after q GEMM

    cvt_bf16_kernel<<<2048, 256, 0, stream>>>(x,   xb,   (H_B * H_SQ * H_D) / 4);
    cvt_bf16_kernel<<<2048, 256, 0, stream>>>(ctx, ctxb, (H_B * H_SK * H_D) / 4);

    wtrans_kernel<<<dim3(32, 32), dim3(32, 8), 0, stream>>>(Wq,  WqT,  H_D, H_D);
    wtrans_kernel<<<dim3(64, 32), dim3(32, 8), 0, stream>>>(Wkv, WkvT, H_D, 2 * H_D);
    wtrans_kernel<<<dim3(32, 32), dim3(32, 8), 0, stream>>>(Wp,  WpT,  H_D, H_D);

    gemm_bt_kernel<0><<<256, 256, 0, stream>>>(xb,   WqT,  bq,  qb, nullptr, H_B * H_SQ, H_D,     H_D);
    gemm_bt_kernel<2><<<1024, 256, 0, stream>>>(ctxb, WkvT, bkv, kb, vTb,    H_B * H_SK, 2 * H_D, H_D);

    attn_kernel<<<H_B * H_NH * (H_SQ / 64), 256, 0, stream>>>(qb, kb, vTb, mask, ab);

    gemm_bt_kernel<1><<<256, 256, 0, stream>>>(ab, WpT, bp, out, nullptr, H_B * H_SQ, H_D, H_D);
}

// Round 11
// 292.171 us; speedup vs baseline: 1.4305x; 1.4305x over previous
//
#include <hip/hip_runtime.h>
#include <stdint.h>

#define H_B  4
#define H_SQ 1024
#define H_SK 2048
#define H_D  1024
#define H_NH 16
#define H_DH 64

typedef __bf16 bf16x8 __attribute__((ext_vector_type(8)));
typedef float  f32x4  __attribute__((ext_vector_type(4)));

__device__ __forceinline__ uint16_t f2bf(float f) {
    union { float f; uint32_t u; } v; v.f = f;
    uint32_t r = v.u + 0x7fffu + ((v.u >> 16) & 1u);
    return (uint16_t)(r >> 16);
}

__device__ __forceinline__ void gload_lds16(const void* g, void* l) {
    __builtin_amdgcn_global_load_lds(
        (const __attribute__((address_space(1))) uint32_t*)g,
        (__attribute__((address_space(3))) uint32_t*)l, 16, 0, 0);
}

#define MFMA_BF16(a, b, c) __builtin_amdgcn_mfma_f32_16x16x32_bf16((a), (b), (c), 0, 0, 0)
#define EXP2(x) __builtin_amdgcn_exp2f(x)

// DPP crosslane (VALU pipe — not DS): xor within 16-lane row groups
template <int CTRL>
__device__ __forceinline__ float dpp_xor(float v) {
    return __builtin_bit_cast(float,
        __builtin_amdgcn_update_dpp(__builtin_bit_cast(int, v),
                                    __builtin_bit_cast(int, v),
                                    CTRL, 0xF, 0xF, false));
}
#define DPP_XOR1 0xB1   // quad_perm(1,0,3,2)
#define DPP_XOR2 0x4E   // quad_perm(2,3,0,1)
#define DPP_XOR4 0x141  // row_half_mirror
#define DPP_XOR8 0x140  // row_mirror

__device__ __forceinline__ float dpp_max16(float v) {
    v = fmaxf(v, dpp_xor<DPP_XOR1>(v));
    v = fmaxf(v, dpp_xor<DPP_XOR2>(v));
    v = fmaxf(v, dpp_xor<DPP_XOR4>(v));
    v = fmaxf(v, dpp_xor<DPP_XOR8>(v));
    return v;
}
__device__ __forceinline__ float dpp_sum16(float v) {
    v += dpp_xor<DPP_XOR1>(v);
    v += dpp_xor<DPP_XOR2>(v);
    v += dpp_xor<DPP_XOR4>(v);
    v += dpp_xor<DPP_XOR8>(v);
    return v;
}

// ---------------- f32 -> bf16 convert (vectorized, grid-stride) ----------------
__global__ void cvt_bf16_kernel(const float* __restrict__ in, uint16_t* __restrict__ out, int n4) {
    int i = blockIdx.x * blockDim.x + threadIdx.x;
    int stride = gridDim.x * blockDim.x;
    for (; i < n4; i += stride) {
        float4 v = ((const float4*)in)[i];
        ushort4 o;
        o.x = f2bf(v.x); o.y = f2bf(v.y); o.z = f2bf(v.z); o.w = f2bf(v.w);
        ((ushort4*)out)[i] = o;
    }
}

// ---------------- weight transpose + convert: W[K][N] f32 -> WT[N][K] bf16 ------
__global__ void wtrans_kernel(const float* __restrict__ W, uint16_t* __restrict__ WT, int K, int N) {
    __shared__ float tile[32][33];
    int n0 = blockIdx.x * 32, k0 = blockIdx.y * 32;
    int tx = threadIdx.x, ty = threadIdx.y;           // block (32,8)
    #pragma unroll
    for (int i = ty; i < 32; i += 8)
        tile[i][tx] = W[(size_t)(k0 + i) * N + n0 + tx];
    __syncthreads();
    #pragma unroll
    for (int i = ty; i < 32; i += 8)
        WT[(size_t)(n0 + i) * K + k0 + tx] = f2bf(tile[tx][i]);
}

// ---------------- GEMM: C[M][N] = A[M][K] @ BT[N][K]^T + bias, bf16 in ----------
// 2-phase double-buffered LDS. MODE 0: bf16 C. MODE 1: f32 C.
// MODE 2 (kv projection): cols < H_D -> kb[row][col] (stride H_D, K-half);
//                         cols >= H_D -> vT[(b*16+hh)*64+dd][sk] transposed,
//                         packed 4 sk per uint2 store. Fuses the old vtrans.
template <int MODE>
__global__ __launch_bounds__(256) void gemm_bt_kernel(
    const uint16_t* __restrict__ A, const uint16_t* __restrict__ BT,
    const float* __restrict__ bias, void* __restrict__ Cv,
    uint16_t* __restrict__ vTb, int M, int N, int K)
{
    __shared__ uint16_t As[2][128 * 32];
    __shared__ uint16_t Bs[2][128 * 32];

    int nbn = N >> 7;
    int nwg = gridDim.x;
    int cpx = nwg >> 3;                         // nwg divisible by 8 for all our shapes
    int wg = blockIdx.x;
    wg = (wg & 7) * cpx + (wg >> 3);            // XCD-aware swizzle (bijective)
    int bm = wg / nbn, bn = wg % nbn;

    int t = threadIdx.x;
    int w = t >> 6, l = t & 63;
    int lr = l & 15, lg = l >> 4;
    int wr = (w >> 1) * 64, wc = (w & 1) * 64;

    const uint16_t* Ab = A + (size_t)bm * 128 * K;
    const uint16_t* Bb = BT + (size_t)bn * 128 * K;

    // per-thread staging chunk geometry: chunk c -> row c>>2, 16B piece c&3
    int ca = w * 64 + l;
    int rowa = ca >> 2, kpa = (ca & 3) * 8;
    int cb = 256 + ca;
    int rowb = cb >> 2, kpb = (cb & 3) * 8;
    int offa = ca * 16;          // linear LDS byte offsets (dest = base + lane*16)
    int offb = cb * 16;

    f32x4 acc[4][4];
    #pragma unroll
    for (int i = 0; i < 4; ++i)
        #pragma unroll
        for (int j = 0; j < 4; ++j) acc[i][j] = {0.f, 0.f, 0.f, 0.f};

    // prologue: stage k0 = 0 into buffer 0
    gload_lds16(Ab + (size_t)rowa * K + kpa, (char*)As[0] + (offa & ~1023));
    gload_lds16(Ab + (size_t)rowb * K + kpb, (char*)As[0] + (offb & ~1023));
    gload_lds16(Bb + (size_t)rowa * K + kpa, (char*)Bs[0] + (offa & ~1023));
    gload_lds16(Bb + (size_t)rowb * K + kpb, (char*)Bs[0] + (offb & ~1023));
    __syncthreads();

    int buf = 0;
    for (int k0 = 0; k0 < K; k0 += 32) {
        if (k0 + 32 < K) {               // stage next K-tile into other buffer
            int kn = k0 + 32;
            gload_lds16(Ab + (size_t)rowa * K + kn + kpa, (char*)As[buf ^ 1] + (offa & ~1023));
            gload_lds16(Ab + (size_t)rowb * K + kn + kpb, (char*)As[buf ^ 1] + (offb & ~1023));
            gload_lds16(Bb + (size_t)rowa * K + kn + kpa, (char*)Bs[buf ^ 1] + (offa & ~1023));
            gload_lds16(Bb + (size_t)rowb * K + kn + kpb, (char*)Bs[buf ^ 1] + (offb & ~1023));
        }
        bf16x8 af[4], bf[4];
        #pragma unroll
        for (int mi = 0; mi < 4; ++mi)
            af[mi] = *(const bf16x8*)&As[buf][(wr + mi * 16 + lr) * 32 + lg * 8];
        #pragma unroll
        for (int ni = 0; ni < 4; ++ni)
            bf[ni] = *(const bf16x8*)&Bs[buf][(wc + ni * 16 + lr) * 32 + lg * 8];
        #pragma unroll
        for (int mi = 0; mi < 4; ++mi)
            #pragma unroll
            for (int ni = 0; ni < 4; ++ni)
                acc[mi][ni] = MFMA_BF16(af[mi], bf[ni], acc[mi][ni]);
        __syncthreads();                 // drains staging vmcnt + read handoff
        buf ^= 1;
    }

    #pragma unroll
    for (int mi = 0; mi < 4; ++mi) {
        #pragma unroll
        for (int ni = 0; ni < 4; ++ni) {
            int col = bn * 128 + wc + ni * 16 + lr;
            float bv = bias[col];
            int row0 = bm * 128 + wr + mi * 16 + lg * 4;
            if constexpr (MODE == 2) {
                if (col < H_D) {         // K-half -> kb[row][col], stride H_D
                    uint16_t* kb = (uint16_t*)Cv;
                    #pragma unroll
                    for (int j = 0; j < 4; ++j)
                        kb[(size_t)(row0 + j) * H_D + col] = f2bf(acc[mi][ni][j] + bv);
                } else {                 // V-half -> vT[(b*16+hh)*64+dd][sk], packed
                    int dall = col - H_D;
                    int hh = dall >> 6, dd = dall & 63;
                    int bb = row0 >> 11, sk0 = row0 & 2047;  // 128-tiles don't cross b
                    uint16_t p0 = f2bf(acc[mi][ni][0] + bv);
                    uint16_t p1 = f2bf(acc[mi][ni][1] + bv);
                    uint16_t p2 = f2bf(acc[mi][ni][2] + bv);
                    uint16_t p3 = f2bf(acc[mi][ni][3] + bv);
                    uint32_t lo = (uint32_t)p0 | ((uint32_t)p1 << 16);
                    uint32_t hi = (uint32_t)p2 | ((uint32_t)p3 << 16);
                    *(uint2*)&vTb[((size_t)(bb * 16 + hh) * 64 + dd) * H_SK + sk0] =
                        make_uint2(lo, hi);
                }
            } else {
                #pragma unroll
                for (int j = 0; j < 4; ++j) {
                    float v = acc[mi][ni][j] + bv;
                    if constexpr (MODE == 0)
                        ((uint16_t*)Cv)[(size_t)(row0 + j) * N + col] = f2bf(v);
                    else
                        ((float*)Cv)[(size_t)(row0 + j) * N + col] = v;
                }
            }
        }
    }
}

// ---------------- flash attention: staged K (r9) + direct-global V (r10) --------
// K double-buffered via global_load_lds (2-phase, both-sides XOR swizzle) — K
// is on the serial critical path so staging stays. V consumed only AFTER
// QK^T+softmax (~500 cy of work), so V fragments load directly from L2
// (panel swizzle keeps the V^T panel XCD-resident); issued at tile top so
// latency hides under QK^T+softmax. Deletes Vs: LDS 41.5 -> 25 KB.
__global__ __launch_bounds__(256) void attn_kernel(
    const uint16_t* __restrict__ qb, const uint16_t* __restrict__ kb,
    const uint16_t* __restrict__ vT, const float* __restrict__ mask,
    uint16_t* __restrict__ ab)
{
    __shared__ uint16_t Ks[2][64 * 64];   // [row k][64 d], rows 128B, swizzled cols
    __shared__ uint16_t p_lds[4][16][68]; // stride 68: b16 writes spread all banks

    int bid = blockIdx.x;
    int xcd = bid & 7;
    int kk = bid >> 3;               // 0..127
    int qt = kk & 15;
    int bh = xcd + 8 * (kk >> 4);    // bijective; panel blocks share bid%8
    int b = bh >> 4, hh = bh & 15;

    int t = threadIdx.x;
    int w = t >> 6, l = t & 63;
    int lr = l & 15, lg = l >> 4;

    // Q fragments straight from global (once per block)
    const uint16_t* qrow = qb + (size_t)(b * H_SQ + qt * 64 + w * 16 + lr) * H_D + hh * H_DH;
    bf16x8 qf0 = *(const bf16x8*)(qrow + lg * 8);
    bf16x8 qf1 = *(const bf16x8*)(qrow + 32 + lg * 8);

    f32x4 acc[4];
    #pragma unroll
    for (int i = 0; i < 4; ++i) acc[i] = {0.f, 0.f, 0.f, 0.f};
    float mrow[4], lsum[4];   // lsum = per-lane PARTIAL (this lane's ni columns)
    #pragma unroll
    for (int j = 0; j < 4; ++j) { mrow[j] = -1e30f; lsum[j] = 0.f; }

    const float SC  = 0.18033688011112042f;   // log2(e)/8
    const float L2E = 1.4426950408889634f;

    // per-lane chunk geometry for K staging (16B chunks, 512 per 64x64 tile)
    // chunk c: row r = c>>3, lds col16 cL = c&7, global col16 = cL ^ (r&7)
    int c0 = w * 64 + l;
    int r0 = c0 >> 3,          gc0 = ((c0 & 7) ^ (r0 & 7)) * 8;
    int c1 = 256 + c0;
    int r1 = c1 >> 3,          gc1 = ((c1 & 7) ^ (r1 & 7)) * 8;
    int ldsoff = (w * 64) * 16;               // wave-uniform byte offset, instr 0
    const uint16_t* kbase = kb + (size_t)b * H_SK * H_D + hh * H_DH;
    const uint16_t* vbase = vT + (size_t)bh * H_DH * H_SK;

    // prologue: stage K tile 0, preload mask(0) premultiplied by log2(e)
    float msk_nxt[4];
    {
        gload_lds16(kbase + (size_t)r0 * H_D + gc0, (char*)Ks[0] + ldsoff);
        gload_lds16(kbase + (size_t)r1 * H_D + gc1, (char*)Ks[0] + ldsoff + 4096);
        #pragma unroll
        for (int ni = 0; ni < 4; ++ni) msk_nxt[ni] = mask[b * H_SK + ni * 16 + lr] * L2E;
    }
    __syncthreads();   // implicit vmcnt(0): K tile 0 landed

    int cur = 0;
    for (int kt = 0; kt < H_SK / 64; ++kt) {
        int sk0 = kt * 64;
        float msk_cur[4];
        #pragma unroll
        for (int ni = 0; ni < 4; ++ni) msk_cur[ni] = msk_nxt[ni];

        // V fragments for THIS tile: issue first (L2-hit latency hides under
        // QK^T + softmax; V^T panel is XCD-L2-resident via panel swizzle)
        bf16x8 vf0[4], vf1[4];
        #pragma unroll
        for (int ni = 0; ni < 4; ++ni) {
            const uint16_t* vp = vbase + (size_t)(ni * 16 + lr) * H_SK + sk0;
            vf0[ni] = *(const bf16x8*)(vp + lg * 8);
            vf1[ni] = *(const bf16x8*)(vp + 32 + lg * 8);
        }

        if (kt + 1 < H_SK / 64) {        // stage next K tile into other buffer
            int sk1 = (kt + 1) * 64;
            int nxt = cur ^ 1;
            gload_lds16(kbase + (size_t)(sk1 + r0) * H_D + gc0, (char*)Ks[nxt] + ldsoff);
            gload_lds16(kbase + (size_t)(sk1 + r1) * H_D + gc1, (char*)Ks[nxt] + ldsoff + 4096);
            #pragma unroll
            for (int ni = 0; ni < 4; ++ni) msk_nxt[ni] = mask[b * H_SK + sk1 + ni * 16 + lr] * L2E;
        }

        const uint16_t* Kb = Ks[cur];
        int sw = (lg ^ (lr & 7)) * 8;    // swizzled col (elements) for frag reads

        // S = Q K^T
        f32x4 s[4];
        #pragma unroll
        for (int ni = 0; ni < 4; ++ni) s[ni] = {0.f, 0.f, 0.f, 0.f};
        #pragma unroll
        for (int ni = 0; ni < 4; ++ni) {
            bf16x8 kf0 = *(const bf16x8*)&Kb[(ni * 16 + lr) * 64 + sw];
            bf16x8 kf1 = *(const bf16x8*)&Kb[(ni * 16 + lr) * 64 + (sw ^ 32)];
            s[ni] = MFMA_BF16(qf0, kf0, s[ni]);
            s[ni] = MFMA_BF16(qf1, kf1, s[ni]);
        }

        // online softmax, exp2 domain; row max via DPP (VALU pipe, no DS)
        float lg2[4][4], mx[4];
        #pragma unroll
        for (int j = 0; j < 4; ++j) {
            float a0 = fmaf(s[0][j], SC, msk_cur[0]);
            float a1 = fmaf(s[1][j], SC, msk_cur[1]);
            float a2 = fmaf(s[2][j], SC, msk_cur[2]);
            float a3 = fmaf(s[3][j], SC, msk_cur[3]);
            lg2[0][j] = a0; lg2[1][j] = a1; lg2[2][j] = a2; lg2[3][j] = a3;
            mx[j] = dpp_max16(fmaxf(fmaxf(a0, a1), fmaxf(a2, a3)));
        }
        // defer-max: only rescale when some row grew past THR=8 (exp2 domain,
        // so P bounded by 2^8=256; f32 lsum/acc have headroom)
        int grow = 0;
        float nm[4];
        #pragma unroll
        for (int j = 0; j < 4; ++j) {
            nm[j] = fmaxf(mrow[j], mx[j]);
            grow |= (mx[j] > mrow[j] + 8.0f) ? 1 : 0;
        }
        if (__any(grow)) {
            #pragma unroll
            for (int j = 0; j < 4; ++j) {
                float alpha = EXP2(mrow[j] - nm[j]);
                mrow[j] = nm[j];
                lsum[j] *= alpha;          // partial: linear in alpha, stays valid
                #pragma unroll
                for (int ni = 0; ni < 4; ++ni) acc[ni][j] *= alpha;
            }
        }
        #pragma unroll
        for (int ni = 0; ni < 4; ++ni)
            #pragma unroll
            for (int j = 0; j < 4; ++j) {
                float p = EXP2(lg2[ni][j] - mrow[j]);
                lsum[j] += p;              // per-lane partial; no cross-lane here
                uint32_t pk;
                asm("v_cvt_pk_bf16_f32 %0, %1, %2" : "=v"(pk) : "v"(p), "v"(p));
                p_lds[w][lg * 4 + j][ni * 16 + lr] = (uint16_t)pk;
            }

        // O += P V  (p_lds wave-private; V already in registers)
        bf16x8 pf0 = *(const bf16x8*)&p_lds[w][lr][lg * 8];
        bf16x8 pf1 = *(const bf16x8*)&p_lds[w][lr][32 + lg * 8];
        #pragma unroll
        for (int ni = 0; ni < 4; ++ni) {
            acc[ni] = MFMA_BF16(pf0, vf0[ni], acc[ni]);
            acc[ni] = MFMA_BF16(pf1, vf1[ni], acc[ni]);
        }

        __syncthreads();   // drains this iter's K gloads + protects Ks buffers
        cur ^= 1;
    }

    // single cross-lane sum reduce at the end (16-lane row groups)
    float inv[4];
    #pragma unroll
    for (int j = 0; j < 4; ++j) inv[j] = 1.0f / dpp_sum16(lsum[j]);
    #pragma unroll
    for (int ni = 0; ni < 4; ++ni)
        #pragma unroll
        for (int j = 0; j < 4; ++j) {
            int row = qt * 64 + w * 16 + lg * 4 + j;
            int col = hh * H_DH + ni * 16 + lr;
            ab[(size_t)(b * H_SQ + row) * H_D + col] = f2bf(acc[ni][j] * inv[j]);
        }
}

// ---------------- host ----------------------------------------------------------
extern "C" void kernel_launch(void* const* d_in, const int* in_sizes, int n_in,
                              void* d_out, int out_size, void* d_ws, size_t ws_size,
                              hipStream_t stream) {
    const float* x    = (const float*)d_in[0];
    const float* ctx  = (const float*)d_in[1];
    const float* mask = (const float*)d_in[2];
    const float* Wq   = (const float*)d_in[3];
    const float* bq   = (const float*)d_in[4];
    const float* Wkv  = (const float*)d_in[5];
    const float* bkv  = (const float*)d_in[6];
    const float* Wp   = (const float*)d_in[7];
    const float* bp   = (const float*)d_in[8];
    float* out = (float*)d_out;

    char* ws = (char*)d_ws;
    uint16_t* xb   = (uint16_t*)(ws + 0);          //  8MB (reused as ab after q GEMM)
    uint16_t* ctxb = (uint16_t*)(ws + 8388608);    // 16MB
    uint16_t* vTb  = (uint16_t*)(ws + 25165824);   // 16MB (written BY kv GEMM -> no alias with ctxb)
    uint16_t* WqT  = (uint16_t*)(ws + 41943040);   //  2MB
    uint16_t* WkvT = (uint16_t*)(ws + 44040192);   //  4MB
    uint16_t* WpT  = (uint16_t*)(ws + 48234496);   //  2MB
    uint16_t* qb   = (uint16_t*)(ws + 50331648);   //  8MB
    uint16_t* kb   = (uint16_t*)(ws + 58720256);   // 16MB -> total 72MB
    uint16_t* ab   = xb;                            // alias: xb dead after q GEMM

    cvt_bf16_kernel<<<2048, 256, 0, stream>>>(x,   xb,   (H_B * H_SQ * H_D) / 4);
    cvt_bf16_kernel<<<2048, 256, 0, stream>>>(ctx, ctxb, (H_B * H_SK * H_D) / 4);

    wtrans_kernel<<<dim3(32, 32), dim3(32, 8), 0, stream>>>(Wq,  WqT,  H_D, H_D);
    wtrans_kernel<<<dim3(64, 32), dim3(32, 8), 0, stream>>>(Wkv, WkvT, H_D, 2 * H_D);
    wtrans_kernel<<<dim3(32, 32), dim3(32, 8), 0, stream>>>(Wp,  WpT,  H_D, H_D);

    gemm_bt_kernel<0><<<256, 256, 0, stream>>>(xb,   WqT,  bq,  qb, nullptr, H_B * H_SQ, H_D,     H_D);
    gemm_bt_kernel<2><<<1024, 256, 0, stream>>>(ctxb, WkvT, bkv, kb, vTb,    H_B * H_SK, 2 * H_D, H_D);

    attn_kernel<<<H_B * H_NH * (H_SQ / 64), 256, 0, stream>>>(qb, kb, vTb, mask, ab);

    gemm_bt_kernel<1><<<256, 256, 0, stream>>>(ab, WpT, bp, out, nullptr, H_B * H_SQ, H_D, H_D);
}

// Round 12
// 222.731 us; speedup vs baseline: 1.8765x; 1.3118x over previous
//
#include <hip/hip_runtime.h>
#include <stdint.h>

#define H_B  4
#define H_SQ 1024
#define H_SK 2048
#define H_D  1024
#define H_NH 16
#define H_DH 64

typedef __bf16 bf16x8 __attribute__((ext_vector_type(8)));
typedef float  f32x4  __attribute__((ext_vector_type(4)));

__device__ __forceinline__ uint16_t f2bf(float f) {
    union { float f; uint32_t u; } v; v.f = f;
    uint32_t r = v.u + 0x7fffu + ((v.u >> 16) & 1u);
    return (uint16_t)(r >> 16);
}

__device__ __forceinline__ void gload_lds16(const void* g, void* l) {
    __builtin_amdgcn_global_load_lds(
        (const __attribute__((address_space(1))) uint32_t*)g,
        (__attribute__((address_space(3))) uint32_t*)l, 16, 0, 0);
}

#define MFMA_BF16(a, b, c) __builtin_amdgcn_mfma_f32_16x16x32_bf16((a), (b), (c), 0, 0, 0)
#define EXP2(x) __builtin_amdgcn_exp2f(x)

// DPP crosslane (VALU pipe — not DS): xor within 16-lane row groups
template <int CTRL>
__device__ __forceinline__ float dpp_xor(float v) {
    return __builtin_bit_cast(float,
        __builtin_amdgcn_update_dpp(__builtin_bit_cast(int, v),
                                    __builtin_bit_cast(int, v),
                                    CTRL, 0xF, 0xF, false));
}
#define DPP_XOR1 0xB1   // quad_perm(1,0,3,2)
#define DPP_XOR2 0x4E   // quad_perm(2,3,0,1)
#define DPP_XOR4 0x141  // row_half_mirror
#define DPP_XOR8 0x140  // row_mirror

__device__ __forceinline__ float dpp_max16(float v) {
    v = fmaxf(v, dpp_xor<DPP_XOR1>(v));
    v = fmaxf(v, dpp_xor<DPP_XOR2>(v));
    v = fmaxf(v, dpp_xor<DPP_XOR4>(v));
    v = fmaxf(v, dpp_xor<DPP_XOR8>(v));
    return v;
}
__device__ __forceinline__ float dpp_sum16(float v) {
    v += dpp_xor<DPP_XOR1>(v);
    v += dpp_xor<DPP_XOR2>(v);
    v += dpp_xor<DPP_XOR4>(v);
    v += dpp_xor<DPP_XOR8>(v);
    return v;
}

// ---------------- f32 -> bf16 convert (vectorized, grid-stride) ----------------
__global__ void cvt_bf16_kernel(const float* __restrict__ in, uint16_t* __restrict__ out, int n4) {
    int i = blockIdx.x * blockDim.x + threadIdx.x;
    int stride = gridDim.x * blockDim.x;
    for (; i < n4; i += stride) {
        float4 v = ((const float4*)in)[i];
        ushort4 o;
        o.x = f2bf(v.x); o.y = f2bf(v.y); o.z = f2bf(v.z); o.w = f2bf(v.w);
        ((ushort4*)out)[i] = o;
    }
}

// ---------------- weight transpose + convert: W[K][N] f32 -> WT[N][K] bf16 ------
__global__ void wtrans_kernel(const float* __restrict__ W, uint16_t* __restrict__ WT, int K, int N) {
    __shared__ float tile[32][33];
    int n0 = blockIdx.x * 32, k0 = blockIdx.y * 32;
    int tx = threadIdx.x, ty = threadIdx.y;           // block (32,8)
    #pragma unroll
    for (int i = ty; i < 32; i += 8)
        tile[i][tx] = W[(size_t)(k0 + i) * N + n0 + tx];
    __syncthreads();
    #pragma unroll
    for (int i = ty; i < 32; i += 8)
        WT[(size_t)(n0 + i) * K + k0 + tx] = f2bf(tile[tx][i]);
}

// ---------------- GEMM: C[M][N] = A[M][K] @ BT[N][K]^T + bias, bf16 in ----------
// 2-phase double-buffered LDS. Template BM: 128 (4x4 acc/wave) or 64 (2x4,
// doubles grid -> fixes 1-block/CU occupancy for the small GEMMs).
// MODE 0: bf16 C. MODE 1: f32 C.
// MODE 2 (kv projection, BM=128 only): cols < H_D -> kb[row][col] (stride H_D);
//   cols >= H_D -> vT[(b*16+hh)*64+dd][sk] transposed, packed uint2 (fused vtrans).
template <int MODE, int BM>
__global__ __launch_bounds__(256) void gemm_bt_kernel(
    const uint16_t* __restrict__ A, const uint16_t* __restrict__ BT,
    const float* __restrict__ bias, void* __restrict__ Cv,
    uint16_t* __restrict__ vTb, int M, int N, int K)
{
    constexpr int MI = BM / 32;              // acc rows of 16x16 frags per wave
    __shared__ uint16_t As[2][BM * 32];
    __shared__ uint16_t Bs[2][128 * 32];

    int nbn = N >> 7;
    int nwg = gridDim.x;
    int cpx = nwg >> 3;                         // nwg divisible by 8 for all our shapes
    int wg = blockIdx.x;
    wg = (wg & 7) * cpx + (wg >> 3);            // XCD-aware swizzle (bijective)
    int bm = wg / nbn, bn = wg % nbn;

    int t = threadIdx.x;
    int w = t >> 6, l = t & 63;
    int lr = l & 15, lg = l >> 4;
    int wr = (w >> 1) * (BM / 2), wc = (w & 1) * 64;

    const uint16_t* Ab = A + (size_t)bm * BM * K;
    const uint16_t* Bb = BT + (size_t)bn * 128 * K;

    // per-thread staging chunk geometry: chunk c -> row c>>2, 16B piece c&3
    int ca = w * 64 + l;
    int rowa = ca >> 2, kpa = (ca & 3) * 8;
    int cb = 256 + ca;
    int rowb = cb >> 2, kpb = (cb & 3) * 8;
    int offa = ca * 16;          // linear LDS byte offsets (dest = base + lane*16)
    int offb = cb * 16;

    f32x4 acc[MI][4];
    #pragma unroll
    for (int i = 0; i < MI; ++i)
        #pragma unroll
        for (int j = 0; j < 4; ++j) acc[i][j] = {0.f, 0.f, 0.f, 0.f};

    // prologue: stage k0 = 0 into buffer 0 (A: BM*32 tile; 64-row tile = 1 instr)
    gload_lds16(Ab + (size_t)rowa * K + kpa, (char*)As[0] + (offa & ~1023));
    if constexpr (BM == 128)
        gload_lds16(Ab + (size_t)rowb * K + kpb, (char*)As[0] + (offb & ~1023));
    gload_lds16(Bb + (size_t)rowa * K + kpa, (char*)Bs[0] + (offa & ~1023));
    gload_lds16(Bb + (size_t)rowb * K + kpb, (char*)Bs[0] + (offb & ~1023));
    __syncthreads();

    int buf = 0;
    for (int k0 = 0; k0 < K; k0 += 32) {
        if (k0 + 32 < K) {               // stage next K-tile into other buffer
            int kn = k0 + 32;
            gload_lds16(Ab + (size_t)rowa * K + kn + kpa, (char*)As[buf ^ 1] + (offa & ~1023));
            if constexpr (BM == 128)
                gload_lds16(Ab + (size_t)rowb * K + kn + kpb, (char*)As[buf ^ 1] + (offb & ~1023));
            gload_lds16(Bb + (size_t)rowa * K + kn + kpa, (char*)Bs[buf ^ 1] + (offa & ~1023));
            gload_lds16(Bb + (size_t)rowb * K + kn + kpb, (char*)Bs[buf ^ 1] + (offb & ~1023));
        }
        bf16x8 af[MI], bf[4];
        #pragma unroll
        for (int mi = 0; mi < MI; ++mi)
            af[mi] = *(const bf16x8*)&As[buf][(wr + mi * 16 + lr) * 32 + lg * 8];
        #pragma unroll
        for (int ni = 0; ni < 4; ++ni)
            bf[ni] = *(const bf16x8*)&Bs[buf][(wc + ni * 16 + lr) * 32 + lg * 8];
        #pragma unroll
        for (int mi = 0; mi < MI; ++mi)
            #pragma unroll
            for (int ni = 0; ni < 4; ++ni)
                acc[mi][ni] = MFMA_BF16(af[mi], bf[ni], acc[mi][ni]);
        __syncthreads();                 // drains staging vmcnt + read handoff
        buf ^= 1;
    }

    #pragma unroll
    for (int mi = 0; mi < MI; ++mi) {
        #pragma unroll
        for (int ni = 0; ni < 4; ++ni) {
            int col = bn * 128 + wc + ni * 16 + lr;
            float bv = bias[col];
            int row0 = bm * BM + wr + mi * 16 + lg * 4;
            if constexpr (MODE == 2) {
                if (col < H_D) {         // K-half -> kb[row][col], stride H_D
                    uint16_t* kb = (uint16_t*)Cv;
                    #pragma unroll
                    for (int j = 0; j < 4; ++j)
                        kb[(size_t)(row0 + j) * H_D + col] = f2bf(acc[mi][ni][j] + bv);
                } else {                 // V-half -> vT[(b*16+hh)*64+dd][sk], packed
                    int dall = col - H_D;
                    int hh = dall >> 6, dd = dall & 63;
                    int bb = row0 >> 11, sk0 = row0 & 2047;  // 128-tiles don't cross b
                    uint16_t p0 = f2bf(acc[mi][ni][0] + bv);
                    uint16_t p1 = f2bf(acc[mi][ni][1] + bv);
                    uint16_t p2 = f2bf(acc[mi][ni][2] + bv);
                    uint16_t p3 = f2bf(acc[mi][ni][3] + bv);
                    uint32_t lo = (uint32_t)p0 | ((uint32_t)p1 << 16);
                    uint32_t hi = (uint32_t)p2 | ((uint32_t)p3 << 16);
                    *(uint2*)&vTb[((size_t)(bb * 16 + hh) * 64 + dd) * H_SK + sk0] =
                        make_uint2(lo, hi);
                }
            } else {
                #pragma unroll
                for (int j = 0; j < 4; ++j) {
                    float v = acc[mi][ni][j] + bv;
                    if constexpr (MODE == 0)
                        ((uint16_t*)Cv)[(size_t)(row0 + j) * N + col] = f2bf(v);
                    else
                        ((float*)Cv)[(size_t)(row0 + j) * N + col] = v;
                }
            }
        }
    }
}

// ---------------- flash attention (verified round-9 kernel, unchanged) ----------
// grid 1024; panel-swizzled decode: the 16 q-tiles of one (b,h) panel share
// bid%8 -> same XCD under round-robin dispatch -> K/V panel fetched into one
// L2 once. K from kb (stride H_D), V^T staged; both via global_load_lds with
// both-sides XOR swizzle, double-buffered, one barrier/tile. DPP reductions.
__global__ __launch_bounds__(256) void attn_kernel(
    const uint16_t* __restrict__ qb, const uint16_t* __restrict__ kb,
    const uint16_t* __restrict__ vT, const float* __restrict__ mask,
    uint16_t* __restrict__ ab)
{
    __shared__ uint16_t Ks[2][64 * 64];   // [row k][64 d], rows 128B, swizzled cols
    __shared__ uint16_t Vs[2][64 * 64];   // [row d][64 k]
    __shared__ uint16_t p_lds[4][16][68]; // stride 68: b16 writes spread all banks

    int bid = blockIdx.x;
    int xcd = bid & 7;
    int kk = bid >> 3;               // 0..127
    int qt = kk & 15;
    int bh = xcd + 8 * (kk >> 4);    // bijective; panel blocks share bid%8
    int b = bh >> 4, hh = bh & 15;

    int t = threadIdx.x;
    int w = t >> 6, l = t & 63;
    int lr = l & 15, lg = l >> 4;

    // Q fragments straight from global (once per block)
    const uint16_t* qrow = qb + (size_t)(b * H_SQ + qt * 64 + w * 16 + lr) * H_D + hh * H_DH;
    bf16x8 qf0 = *(const bf16x8*)(qrow + lg * 8);
    bf16x8 qf1 = *(const bf16x8*)(qrow + 32 + lg * 8);

    f32x4 acc[4];
    #pragma unroll
    for (int i = 0; i < 4; ++i) acc[i] = {0.f, 0.f, 0.f, 0.f};
    float mrow[4], lsum[4];   // lsum = per-lane PARTIAL (this lane's ni columns)
    #pragma unroll
    for (int j = 0; j < 4; ++j) { mrow[j] = -1e30f; lsum[j] = 0.f; }

    const float SC  = 0.18033688011112042f;   // log2(e)/8
    const float L2E = 1.4426950408889634f;

    // per-lane chunk geometry for staging (16B chunks, 512 per 64x64 tile)
    // chunk c: row r = c>>3, lds col16 cL = c&7, global col16 = cL ^ (r&7)
    int c0 = w * 64 + l;
    int r0 = c0 >> 3,          gc0 = ((c0 & 7) ^ (r0 & 7)) * 8;
    int c1 = 256 + c0;
    int r1 = c1 >> 3,          gc1 = ((c1 & 7) ^ (r1 & 7)) * 8;
    int ldsoff = (w * 64) * 16;               // wave-uniform byte offset, instr 0
    const uint16_t* kbase = kb + (size_t)b * H_SK * H_D + hh * H_DH;
    const uint16_t* vbase = vT + (size_t)bh * H_DH * H_SK;

    // prologue: stage tile 0, preload mask(0) premultiplied by log2(e)
    float msk_nxt[4];
    {
        gload_lds16(kbase + (size_t)r0 * H_D + gc0, (char*)Ks[0] + ldsoff);
        gload_lds16(kbase + (size_t)r1 * H_D + gc1, (char*)Ks[0] + ldsoff + 4096);
        gload_lds16(vbase + (size_t)r0 * H_SK + gc0, (char*)Vs[0] + ldsoff);
        gload_lds16(vbase + (size_t)r1 * H_SK + gc1, (char*)Vs[0] + ldsoff + 4096);
        #pragma unroll
        for (int ni = 0; ni < 4; ++ni) msk_nxt[ni] = mask[b * H_SK + ni * 16 + lr] * L2E;
    }
    __syncthreads();   // implicit vmcnt(0): tile 0 landed

    int cur = 0;
    for (int kt = 0; kt < H_SK / 64; ++kt) {
        float msk_cur[4];
        #pragma unroll
        for (int ni = 0; ni < 4; ++ni) msk_cur[ni] = msk_nxt[ni];

        if (kt + 1 < H_SK / 64) {        // stage next tile into other buffer
            int sk1 = (kt + 1) * 64;
            int nxt = cur ^ 1;
            gload_lds16(kbase + (size_t)(sk1 + r0) * H_D + gc0, (char*)Ks[nxt] + ldsoff);
            gload_lds16(kbase + (size_t)(sk1 + r1) * H_D + gc1, (char*)Ks[nxt] + ldsoff + 4096);
            // V^T rows are d (stride H_SK); k-offset sk1 adds AFTER row*stride
            gload_lds16(vbase + (size_t)r0 * H_SK + sk1 + gc0, (char*)Vs[nxt] + ldsoff);
            gload_lds16(vbase + (size_t)r1 * H_SK + sk1 + gc1, (char*)Vs[nxt] + ldsoff + 4096);
            #pragma unroll
            for (int ni = 0; ni < 4; ++ni) msk_nxt[ni] = mask[b * H_SK + sk1 + ni * 16 + lr] * L2E;
        }

        const uint16_t* Kb = Ks[cur];
        const uint16_t* Vb = Vs[cur];
        int sw = (lg ^ (lr & 7)) * 8;    // swizzled col (elements) for frag reads

        // S = Q K^T
        f32x4 s[4];
        #pragma unroll
        for (int ni = 0; ni < 4; ++ni) s[ni] = {0.f, 0.f, 0.f, 0.f};
        #pragma unroll
        for (int ni = 0; ni < 4; ++ni) {
            bf16x8 kf0 = *(const bf16x8*)&Kb[(ni * 16 + lr) * 64 + sw];
            bf16x8 kf1 = *(const bf16x8*)&Kb[(ni * 16 + lr) * 64 + (sw ^ 32)];
            s[ni] = MFMA_BF16(qf0, kf0, s[ni]);
            s[ni] = MFMA_BF16(qf1, kf1, s[ni]);
        }

        // online softmax, exp2 domain; row max via DPP (VALU pipe, no DS)
        float lg2[4][4], mx[4];
        #pragma unroll
        for (int j = 0; j < 4; ++j) {
            float a0 = fmaf(s[0][j], SC, msk_cur[0]);
            float a1 = fmaf(s[1][j], SC, msk_cur[1]);
            float a2 = fmaf(s[2][j], SC, msk_cur[2]);
            float a3 = fmaf(s[3][j], SC, msk_cur[3]);
            lg2[0][j] = a0; lg2[1][j] = a1; lg2[2][j] = a2; lg2[3][j] = a3;
            mx[j] = dpp_max16(fmaxf(fmaxf(a0, a1), fmaxf(a2, a3)));
        }
        // defer-max: only rescale when some row grew past THR=8 (exp2 domain,
        // so P bounded by 2^8=256; f32 lsum/acc have headroom)
        int grow = 0;
        float nm[4];
        #pragma unroll
        for (int j = 0; j < 4; ++j) {
            nm[j] = fmaxf(mrow[j], mx[j]);
            grow |= (mx[j] > mrow[j] + 8.0f) ? 1 : 0;
        }
        if (__any(grow)) {
            #pragma unroll
            for (int j = 0; j < 4; ++j) {
                float alpha = EXP2(mrow[j] - nm[j]);
                mrow[j] = nm[j];
                lsum[j] *= alpha;          // partial: linear in alpha, stays valid
                #pragma unroll
                for (int ni = 0; ni < 4; ++ni) acc[ni][j] *= alpha;
            }
        }
        #pragma unroll
        for (int ni = 0; ni < 4; ++ni)
            #pragma unroll
            for (int j = 0; j < 4; ++j) {
                float p = EXP2(lg2[ni][j] - mrow[j]);
                lsum[j] += p;              // per-lane partial; no cross-lane here
                uint32_t pk;
                asm("v_cvt_pk_bf16_f32 %0, %1, %2" : "=v"(pk) : "v"(p), "v"(p));
                p_lds[w][lg * 4 + j][ni * 16 + lr] = (uint16_t)pk;
            }

        // O += P V  (p_lds wave-private; compiler inserts lgkm waits)
        bf16x8 pf0 = *(const bf16x8*)&p_lds[w][lr][lg * 8];
        bf16x8 pf1 = *(const bf16x8*)&p_lds[w][lr][32 + lg * 8];
        #pragma unroll
        for (int ni = 0; ni < 4; ++ni) {
            bf16x8 vf0 = *(const bf16x8*)&Vb[(ni * 16 + lr) * 64 + sw];
            bf16x8 vf1 = *(const bf16x8*)&Vb[(ni * 16 + lr) * 64 + (sw ^ 32)];
            acc[ni] = MFMA_BF16(pf0, vf0, acc[ni]);
            acc[ni] = MFMA_BF16(pf1, vf1, acc[ni]);
        }

        __syncthreads();   // drains this iter's gloads (vmcnt 0) + protects buffers
        cur ^= 1;
    }

    // single cross-lane sum reduce at the end (16-lane row groups)
    float inv[4];
    #pragma unroll
    for (int j = 0; j < 4; ++j) inv[j] = 1.0f / dpp_sum16(lsum[j]);
    #pragma unroll
    for (int ni = 0; ni < 4; ++ni)
        #pragma unroll
        for (int j = 0; j < 4; ++j) {
            int row = qt * 64 + w * 16 + lg * 4 + j;
            int col = hh * H_DH + ni * 16 + lr;
            ab[(size_t)(b * H_SQ + row) * H_D + col] = f2bf(acc[ni][j] * inv[j]);
        }
}

// ---------------- host ----------------------------------------------------------
extern "C" void kernel_launch(void* const* d_in, const int* in_sizes, int n_in,
                              void* d_out, int out_size, void* d_ws, size_t ws_size,
                              hipStream_t stream) {
    const float* x    = (const float*)d_in[0];
    const float* ctx  = (const float*)d_in[1];
    const float* mask = (const float*)d_in[2];
    const float* Wq   = (const float*)d_in[3];
    const float* bq   = (const float*)d_in[4];
    const float* Wkv  = (const float*)d_in[5];
    const float* bkv  = (const float*)d_in[6];
    const float* Wp   = (const float*)d_in[7];
    const float* bp   = (const float*)d_in[8];
    float* out = (float*)d_out;

    char* ws = (char*)d_ws;
    uint16_t* xb   = (uint16_t*)(ws + 0);          //  8MB (reused as ab after q GEMM)
    uint16_t* ctxb = (uint16_t*)(ws + 8388608);    // 16MB
    uint16_t* vTb  = (uint16_t*)(ws + 25165824);   // 16MB (written BY kv GEMM -> no alias with ctxb)
    uint16_t* WqT  = (uint16_t*)(ws + 41943040);   //  2MB
    uint16_t* WkvT = (uint16_t*)(ws + 44040192);   //  4MB
    uint16_t* WpT  = (uint16_t*)(ws + 48234496);   //  2MB
    uint16_t* qb   = (uint16_t*)(ws + 50331648);   //  8MB
    uint16_t* kb   = (uint16_t*)(ws + 58720256);   // 16MB -> total 72MB
    uint16_t* ab   = xb;                            // alias: xb dead after q GEMM

    cvt_bf16_kernel<<<2048, 256, 0, stream>>>(x,   xb,   (H_B * H_SQ * H_D) / 4);
    cvt_bf16_kernel<<<2048, 256, 0, stream>>>(ctx, ctxb, (H_B * H_SK * H_D) / 4);

    wtrans_kernel<<<dim3(32, 32), dim3(32, 8), 0, stream>>>(Wq,  WqT,  H_D, H_D);
    wtrans_kernel<<<dim3(64, 32), dim3(32, 8), 0, stream>>>(Wkv, WkvT, H_D, 2 * H_D);
    wtrans_kernel<<<dim3(32, 32), dim3(32, 8), 0, stream>>>(Wp,  WpT,  H_D, H_D);

    gemm_bt_kernel<0, 64><<<512, 256, 0, stream>>>(xb,   WqT,  bq,  qb, nullptr, H_B * H_SQ, H_D,     H_D);
    gemm_bt_kernel<2, 128><<<1024, 256, 0, stream>>>(ctxb, WkvT, bkv, kb, vTb,   H_B * H_SK, 2 * H_D, H_D);

    attn_kernel<<<H_B * H_NH * (H_SQ / 64), 256, 0, stream>>>(qb, kb, vTb, mask, ab);

    gemm_bt_kernel<1, 64><<<512, 256, 0, stream>>>(ab, WpT, bp, out, nullptr, H_B * H_SQ, H_D, H_D);
}

// Round 13
// 197.547 us; speedup vs baseline: 2.1157x; 1.1275x over previous
//
#include <hip/hip_runtime.h>
#include <stdint.h>

#define H_B  4
#define H_SQ 1024
#define H_SK 2048
#define H_D  1024
#define H_NH 16
#define H_DH 64

typedef __bf16 bf16x8 __attribute__((ext_vector_type(8)));
typedef float  f32x4  __attribute__((ext_vector_type(4)));

__device__ __forceinline__ uint16_t f2bf(float f) {
    union { float f; uint32_t u; } v; v.f = f;
    uint32_t r = v.u + 0x7fffu + ((v.u >> 16) & 1u);
    return (uint16_t)(r >> 16);
}

__device__ __forceinline__ void gload_lds16(const void* g, void* l) {
    __builtin_amdgcn_global_load_lds(
        (const __attribute__((address_space(1))) uint32_t*)g,
        (__attribute__((address_space(3))) uint32_t*)l, 16, 0, 0);
}

#define MFMA_BF16(a, b, c) __builtin_amdgcn_mfma_f32_16x16x32_bf16((a), (b), (c), 0, 0, 0)
#define EXP2(x) __builtin_amdgcn_exp2f(x)

// DPP crosslane (VALU pipe — not DS): xor within 16-lane row groups
template <int CTRL>
__device__ __forceinline__ float dpp_xor(float v) {
    return __builtin_bit_cast(float,
        __builtin_amdgcn_update_dpp(__builtin_bit_cast(int, v),
                                    __builtin_bit_cast(int, v),
                                    CTRL, 0xF, 0xF, false));
}
#define DPP_XOR1 0xB1   // quad_perm(1,0,3,2)
#define DPP_XOR2 0x4E   // quad_perm(2,3,0,1)
#define DPP_XOR4 0x141  // row_half_mirror
#define DPP_XOR8 0x140  // row_mirror

__device__ __forceinline__ float dpp_max16(float v) {
    v = fmaxf(v, dpp_xor<DPP_XOR1>(v));
    v = fmaxf(v, dpp_xor<DPP_XOR2>(v));
    v = fmaxf(v, dpp_xor<DPP_XOR4>(v));
    v = fmaxf(v, dpp_xor<DPP_XOR8>(v));
    return v;
}
__device__ __forceinline__ float dpp_sum16(float v) {
    v += dpp_xor<DPP_XOR1>(v);
    v += dpp_xor<DPP_XOR2>(v);
    v += dpp_xor<DPP_XOR4>(v);
    v += dpp_xor<DPP_XOR8>(v);
    return v;
}

// ---------------- f32 -> bf16 convert, both inputs in one dispatch --------------
__global__ void cvt2_bf16_kernel(const float* __restrict__ a, uint16_t* __restrict__ oa, int n4a,
                                 const float* __restrict__ b, uint16_t* __restrict__ ob, int n4b) {
    int i = blockIdx.x * blockDim.x + threadIdx.x;
    int stride = gridDim.x * blockDim.x;
    int tot = n4a + n4b;
    for (; i < tot; i += stride) {
        float4 v;
        if (i < n4a) v = ((const float4*)a)[i];
        else         v = ((const float4*)b)[i - n4a];
        ushort4 o;
        o.x = f2bf(v.x); o.y = f2bf(v.y); o.z = f2bf(v.z); o.w = f2bf(v.w);
        if (i < n4a) ((ushort4*)oa)[i] = o;
        else         ((ushort4*)ob)[i - n4a] = o;
    }
}

// ---------------- all 3 weight transposes (K=1024) in one dispatch --------------
__global__ void wtrans3_kernel(const float* __restrict__ Wq, uint16_t* __restrict__ WqT,
                               const float* __restrict__ Wkv, uint16_t* __restrict__ WkvT,
                               const float* __restrict__ Wp, uint16_t* __restrict__ WpT) {
    __shared__ float tile[32][33];
    int bx = blockIdx.x;                 // 0..127 along n: 32 Wq | 64 Wkv | 32 Wp
    const float* W; uint16_t* WT; int N, n0;
    if (bx < 32)      { W = Wq;  WT = WqT;  N = 1024; n0 = bx * 32; }
    else if (bx < 96) { W = Wkv; WT = WkvT; N = 2048; n0 = (bx - 32) * 32; }
    else              { W = Wp;  WT = WpT;  N = 1024; n0 = (bx - 96) * 32; }
    int k0 = blockIdx.y * 32;
    int tx = threadIdx.x, ty = threadIdx.y;          // block (32,8)
    #pragma unroll
    for (int i = ty; i < 32; i += 8)
        tile[i][tx] = W[(size_t)(k0 + i) * N + n0 + tx];
    __syncthreads();
    #pragma unroll
    for (int i = ty; i < 32; i += 8)
        WT[(size_t)(n0 + i) * 1024 + k0 + tx] = f2bf(tile[tx][i]);
}

// ---------------- GEMM: C[M][N] = A[M][K] @ BT[N][K]^T + bias, bf16 in ----------
// 2-phase double-buffered LDS. Template BM: 128 (4x4 acc/wave) or 64 (2x4,
// doubles grid -> fixes 1-block/CU occupancy for the small GEMMs).
// MODE 0: bf16 C. MODE 1: f32 C.
// MODE 2 (kv projection, BM=128 only): cols < H_D -> kb[row][col] (stride H_D);
//   cols >= H_D -> vT[(b*16+hh)*64+dd][sk] transposed, packed uint2 (fused vtrans).
template <int MODE, int BM>
__global__ __launch_bounds__(256) void gemm_bt_kernel(
    const uint16_t* __restrict__ A, const uint16_t* __restrict__ BT,
    const float* __restrict__ bias, void* __restrict__ Cv,
    uint16_t* __restrict__ vTb, int M, int N, int K)
{
    constexpr int MI = BM / 32;              // acc rows of 16x16 frags per wave
    __shared__ uint16_t As[2][BM * 32];
    __shared__ uint16_t Bs[2][128 * 32];

    int nbn = N >> 7;
    int nwg = gridDim.x;
    int cpx = nwg >> 3;                         // nwg divisible by 8 for all our shapes
    int wg = blockIdx.x;
    wg = (wg & 7) * cpx + (wg >> 3);            // XCD-aware swizzle (bijective)
    int bm = wg / nbn, bn = wg % nbn;

    int t = threadIdx.x;
    int w = t >> 6, l = t & 63;
    int lr = l & 15, lg = l >> 4;
    int wr = (w >> 1) * (BM / 2), wc = (w & 1) * 64;

    const uint16_t* Ab = A + (size_t)bm * BM * K;
    const uint16_t* Bb = BT + (size_t)bn * 128 * K;

    // per-thread staging chunk geometry: chunk c -> row c>>2, 16B piece c&3
    int ca = w * 64 + l;
    int rowa = ca >> 2, kpa = (ca & 3) * 8;
    int cb = 256 + ca;
    int rowb = cb >> 2, kpb = (cb & 3) * 8;
    int offa = ca * 16;          // linear LDS byte offsets (dest = base + lane*16)
    int offb = cb * 16;

    f32x4 acc[MI][4];
    #pragma unroll
    for (int i = 0; i < MI; ++i)
        #pragma unroll
        for (int j = 0; j < 4; ++j) acc[i][j] = {0.f, 0.f, 0.f, 0.f};

    // prologue: stage k0 = 0 into buffer 0 (A: BM*32 tile; 64-row tile = 1 instr)
    gload_lds16(Ab + (size_t)rowa * K + kpa, (char*)As[0] + (offa & ~1023));
    if constexpr (BM == 128)
        gload_lds16(Ab + (size_t)rowb * K + kpb, (char*)As[0] + (offb & ~1023));
    gload_lds16(Bb + (size_t)rowa * K + kpa, (char*)Bs[0] + (offa & ~1023));
    gload_lds16(Bb + (size_t)rowb * K + kpb, (char*)Bs[0] + (offb & ~1023));
    __syncthreads();

    int buf = 0;
    for (int k0 = 0; k0 < K; k0 += 32) {
        if (k0 + 32 < K) {               // stage next K-tile into other buffer
            int kn = k0 + 32;
            gload_lds16(Ab + (size_t)rowa * K + kn + kpa, (char*)As[buf ^ 1] + (offa & ~1023));
            if constexpr (BM == 128)
                gload_lds16(Ab + (size_t)rowb * K + kn + kpb, (char*)As[buf ^ 1] + (offb & ~1023));
            gload_lds16(Bb + (size_t)rowa * K + kn + kpa, (char*)Bs[buf ^ 1] + (offa & ~1023));
            gload_lds16(Bb + (size_t)rowb * K + kn + kpb, (char*)Bs[buf ^ 1] + (offb & ~1023));
        }
        bf16x8 af[MI], bf[4];
        #pragma unroll
        for (int mi = 0; mi < MI; ++mi)
            af[mi] = *(const bf16x8*)&As[buf][(wr + mi * 16 + lr) * 32 + lg * 8];
        #pragma unroll
        for (int ni = 0; ni < 4; ++ni)
            bf[ni] = *(const bf16x8*)&Bs[buf][(wc + ni * 16 + lr) * 32 + lg * 8];
        #pragma unroll
        for (int mi = 0; mi < MI; ++mi)
            #pragma unroll
            for (int ni = 0; ni < 4; ++ni)
                acc[mi][ni] = MFMA_BF16(af[mi], bf[ni], acc[mi][ni]);
        __syncthreads();                 // drains staging vmcnt + read handoff
        buf ^= 1;
    }

    #pragma unroll
    for (int mi = 0; mi < MI; ++mi) {
        #pragma unroll
        for (int ni = 0; ni < 4; ++ni) {
            int col = bn * 128 + wc + ni * 16 + lr;
            float bv = bias[col];
            int row0 = bm * BM + wr + mi * 16 + lg * 4;
            if constexpr (MODE == 2) {
                if (col < H_D) {         // K-half -> kb[row][col], stride H_D
                    uint16_t* kb = (uint16_t*)Cv;
                    #pragma unroll
                    for (int j = 0; j < 4; ++j)
                        kb[(size_t)(row0 + j) * H_D + col] = f2bf(acc[mi][ni][j] + bv);
                } else {                 // V-half -> vT[(b*16+hh)*64+dd][sk], packed
                    int dall = col - H_D;
                    int hh = dall >> 6, dd = dall & 63;
                    int bb = row0 >> 11, sk0 = row0 & 2047;  // 128-tiles don't cross b
                    uint16_t p0 = f2bf(acc[mi][ni][0] + bv);
                    uint16_t p1 = f2bf(acc[mi][ni][1] + bv);
                    uint16_t p2 = f2bf(acc[mi][ni][2] + bv);
                    uint16_t p3 = f2bf(acc[mi][ni][3] + bv);
                    uint32_t lo = (uint32_t)p0 | ((uint32_t)p1 << 16);
                    uint32_t hi = (uint32_t)p2 | ((uint32_t)p3 << 16);
                    *(uint2*)&vTb[((size_t)(bb * 16 + hh) * 64 + dd) * H_SK + sk0] =
                        make_uint2(lo, hi);
                }
            } else {
                #pragma unroll
                for (int j = 0; j < 4; ++j) {
                    float v = acc[mi][ni][j] + bv;
                    if constexpr (MODE == 0)
                        ((uint16_t*)Cv)[(size_t)(row0 + j) * N + col] = f2bf(v);
                    else
                        ((float*)Cv)[(size_t)(row0 + j) * N + col] = v;
                }
            }
        }
    }
}

// ---------------- flash attention (r9 math; p_lds stride 64 + row-XOR) ----------
// grid 1024; panel-swizzled decode pins each (b,h) panel to one XCD's L2.
// K/V double-buffered via global_load_lds (both-sides XOR swizzle), one
// barrier/tile. p_lds now [4][16][64] with col ^= ((q&7)<<3): LDS total
// 40960 B -> EXACTLY 4 blocks/CU (was 3 at stride 68). Round-trip: write
// (q=lg*4+j, k=ni*16+lr) at col k^xkey where xkey=((lg&1)<<5)|(j<<3) ==
// ((q&7)<<3); read row lr applies the same key, XOR is 8-aligned so b128
// reads stay contiguous.
__global__ __launch_bounds__(256) void attn_kernel(
    const uint16_t* __restrict__ qb, const uint16_t* __restrict__ kb,
    const uint16_t* __restrict__ vT, const float* __restrict__ mask,
    uint16_t* __restrict__ ab)
{
    __shared__ uint16_t Ks[2][64 * 64];   // [row k][64 d], rows 128B, swizzled cols
    __shared__ uint16_t Vs[2][64 * 64];   // [row d][64 k]
    __shared__ uint16_t p_lds[4][16][64]; // stride 64 + row-XOR -> 8192 B

    int bid = blockIdx.x;
    int xcd = bid & 7;
    int kk = bid >> 3;               // 0..127
    int qt = kk & 15;
    int bh = xcd + 8 * (kk >> 4);    // bijective; panel blocks share bid%8
    int b = bh >> 4, hh = bh & 15;

    int t = threadIdx.x;
    int w = t >> 6, l = t & 63;
    int lr = l & 15, lg = l >> 4;

    // Q fragments straight from global (once per block)
    const uint16_t* qrow = qb + (size_t)(b * H_SQ + qt * 64 + w * 16 + lr) * H_D + hh * H_DH;
    bf16x8 qf0 = *(const bf16x8*)(qrow + lg * 8);
    bf16x8 qf1 = *(const bf16x8*)(qrow + 32 + lg * 8);

    f32x4 acc[4];
    #pragma unroll
    for (int i = 0; i < 4; ++i) acc[i] = {0.f, 0.f, 0.f, 0.f};
    float mrow[4], lsum[4];   // lsum = per-lane PARTIAL (this lane's ni columns)
    #pragma unroll
    for (int j = 0; j < 4; ++j) { mrow[j] = -1e30f; lsum[j] = 0.f; }

    const float SC  = 0.18033688011112042f;   // log2(e)/8
    const float L2E = 1.4426950408889634f;

    // per-lane chunk geometry for staging (16B chunks, 512 per 64x64 tile)
    // chunk c: row r = c>>3, lds col16 cL = c&7, global col16 = cL ^ (r&7)
    int c0 = w * 64 + l;
    int r0 = c0 >> 3,          gc0 = ((c0 & 7) ^ (r0 & 7)) * 8;
    int c1 = 256 + c0;
    int r1 = c1 >> 3,          gc1 = ((c1 & 7) ^ (r1 & 7)) * 8;
    int ldsoff = (w * 64) * 16;               // wave-uniform byte offset, instr 0
    const uint16_t* kbase = kb + (size_t)b * H_SK * H_D + hh * H_DH;
    const uint16_t* vbase = vT + (size_t)bh * H_DH * H_SK;

    // p_lds XOR keys
    int xkbase = (lg & 1) << 5;               // write key base; | (j<<3) per j
    int rdkey  = (lr & 7) << 3;               // read key for row lr

    // prologue: stage tile 0, preload mask(0) premultiplied by log2(e)
    float msk_nxt[4];
    {
        gload_lds16(kbase + (size_t)r0 * H_D + gc0, (char*)Ks[0] + ldsoff);
        gload_lds16(kbase + (size_t)r1 * H_D + gc1, (char*)Ks[0] + ldsoff + 4096);
        gload_lds16(vbase + (size_t)r0 * H_SK + gc0, (char*)Vs[0] + ldsoff);
        gload_lds16(vbase + (size_t)r1 * H_SK + gc1, (char*)Vs[0] + ldsoff + 4096);
        #pragma unroll
        for (int ni = 0; ni < 4; ++ni) msk_nxt[ni] = mask[b * H_SK + ni * 16 + lr] * L2E;
    }
    __syncthreads();   // implicit vmcnt(0): tile 0 landed

    int cur = 0;
    for (int kt = 0; kt < H_SK / 64; ++kt) {
        float msk_cur[4];
        #pragma unroll
        for (int ni = 0; ni < 4; ++ni) msk_cur[ni] = msk_nxt[ni];

        if (kt + 1 < H_SK / 64) {        // stage next tile into other buffer
            int sk1 = (kt + 1) * 64;
            int nxt = cur ^ 1;
            gload_lds16(kbase + (size_t)(sk1 + r0) * H_D + gc0, (char*)Ks[nxt] + ldsoff);
            gload_lds16(kbase + (size_t)(sk1 + r1) * H_D + gc1, (char*)Ks[nxt] + ldsoff + 4096);
            // V^T rows are d (stride H_SK); k-offset sk1 adds AFTER row*stride
            gload_lds16(vbase + (size_t)r0 * H_SK + sk1 + gc0, (char*)Vs[nxt] + ldsoff);
            gload_lds16(vbase + (size_t)r1 * H_SK + sk1 + gc1, (char*)Vs[nxt] + ldsoff + 4096);
            #pragma unroll
            for (int ni = 0; ni < 4; ++ni) msk_nxt[ni] = mask[b * H_SK + sk1 + ni * 16 + lr] * L2E;
        }

        const uint16_t* Kb = Ks[cur];
        const uint16_t* Vb = Vs[cur];
        int sw = (lg ^ (lr & 7)) * 8;    // swizzled col (elements) for frag reads

        // S = Q K^T
        f32x4 s[4];
        #pragma unroll
        for (int ni = 0; ni < 4; ++ni) s[ni] = {0.f, 0.f, 0.f, 0.f};
        #pragma unroll
        for (int ni = 0; ni < 4; ++ni) {
            bf16x8 kf0 = *(const bf16x8*)&Kb[(ni * 16 + lr) * 64 + sw];
            bf16x8 kf1 = *(const bf16x8*)&Kb[(ni * 16 + lr) * 64 + (sw ^ 32)];
            s[ni] = MFMA_BF16(qf0, kf0, s[ni]);
            s[ni] = MFMA_BF16(qf1, kf1, s[ni]);
        }

        // online softmax, exp2 domain; row max via DPP (VALU pipe, no DS)
        float lg2[4][4], mx[4];
        #pragma unroll
        for (int j = 0; j < 4; ++j) {
            float a0 = fmaf(s[0][j], SC, msk_cur[0]);
            float a1 = fmaf(s[1][j], SC, msk_cur[1]);
            float a2 = fmaf(s[2][j], SC, msk_cur[2]);
            float a3 = fmaf(s[3][j], SC, msk_cur[3]);
            lg2[0][j] = a0; lg2[1][j] = a1; lg2[2][j] = a2; lg2[3][j] = a3;
            mx[j] = dpp_max16(fmaxf(fmaxf(a0, a1), fmaxf(a2, a3)));
        }
        // defer-max: only rescale when some row grew past THR=8 (exp2 domain,
        // so P bounded by 2^8=256; f32 lsum/acc have headroom)
        int grow = 0;
        float nm[4];
        #pragma unroll
        for (int j = 0; j < 4; ++j) {
            nm[j] = fmaxf(mrow[j], mx[j]);
            grow |= (mx[j] > mrow[j] + 8.0f) ? 1 : 0;
        }
        if (__any(grow)) {
            #pragma unroll
            for (int j = 0; j < 4; ++j) {
                float alpha = EXP2(mrow[j] - nm[j]);
                mrow[j] = nm[j];
                lsum[j] *= alpha;          // partial: linear in alpha, stays valid
                #pragma unroll
                for (int ni = 0; ni < 4; ++ni) acc[ni][j] *= alpha;
            }
        }
        #pragma unroll
        for (int ni = 0; ni < 4; ++ni)
            #pragma unroll
            for (int j = 0; j < 4; ++j) {
                float p = EXP2(lg2[ni][j] - mrow[j]);
                lsum[j] += p;              // per-lane partial; no cross-lane here
                uint32_t pk;
                asm("v_cvt_pk_bf16_f32 %0, %1, %2" : "=v"(pk) : "v"(p), "v"(p));
                p_lds[w][lg * 4 + j][(ni * 16 + lr) ^ (xkbase | (j << 3))] = (uint16_t)pk;
            }

        // O += P V  (p_lds wave-private; compiler inserts lgkm waits)
        int pc0 = (lg * 8) ^ rdkey;
        bf16x8 pf0 = *(const bf16x8*)&p_lds[w][lr][pc0];
        bf16x8 pf1 = *(const bf16x8*)&p_lds[w][lr][pc0 ^ 32];
        #pragma unroll
        for (int ni = 0; ni < 4; ++ni) {
            bf16x8 vf0 = *(const bf16x8*)&Vb[(ni * 16 + lr) * 64 + sw];
            bf16x8 vf1 = *(const bf16x8*)&Vb[(ni * 16 + lr) * 64 + (sw ^ 32)];
            acc[ni] = MFMA_BF16(pf0, vf0, acc[ni]);
            acc[ni] = MFMA_BF16(pf1, vf1, acc[ni]);
        }

        __syncthreads();   // drains this iter's gloads (vmcnt 0) + protects buffers
        cur ^= 1;
    }

    // single cross-lane sum reduce at the end (16-lane row groups)
    float inv[4];
    #pragma unroll
    for (int j = 0; j < 4; ++j) inv[j] = 1.0f / dpp_sum16(lsum[j]);
    #pragma unroll
    for (int ni = 0; ni < 4; ++ni)
        #pragma unroll
        for (int j = 0; j < 4; ++j) {
            int row = qt * 64 + w * 16 + lg * 4 + j;
            int col = hh * H_DH + ni * 16 + lr;
            ab[(size_t)(b * H_SQ + row) * H_D + col] = f2bf(acc[ni][j] * inv[j]);
        }
}

// ---------------- host ----------------------------------------------------------
extern "C" void kernel_launch(void* const* d_in, const int* in_sizes, int n_in,
                              void* d_out, int out_size, void* d_ws, size_t ws_size,
                              hipStream_t stream) {
    const float* x    = (const float*)d_in[0];
    const float* ctx  = (const float*)d_in[1];
    const float* mask = (const float*)d_in[2];
    const float* Wq   = (const float*)d_in[3];
    const float* bq   = (const float*)d_in[4];
    const float* Wkv  = (const float*)d_in[5];
    const float* bkv  = (const float*)d_in[6];
    const float* Wp   = (const float*)d_in[7];
    const float* bp   = (const float*)d_in[8];
    float* out = (float*)d_out;

    char* ws = (char*)d_ws;
    uint16_t* xb   = (uint16_t*)(ws + 0);          //  8MB (reused as ab after q GEMM)
    uint16_t* ctxb = (uint16_t*)(ws + 8388608);    // 16MB
    uint16_t* vTb  = (uint16_t*)(ws + 25165824);   // 16MB (written BY kv GEMM -> no alias with ctxb)
    uint16_t* WqT  = (uint16_t*)(ws + 41943040);   //  2MB
    uint16_t* WkvT = (uint16_t*)(ws + 44040192);   //  4MB
    uint16_t* WpT  = (uint16_t*)(ws + 48234496);   //  2MB
    uint16_t* qb   = (uint16_t*)(ws + 50331648);   //  8MB
    uint16_t* kb   = (uint16_t*)(ws + 58720256);   // 16MB -> total 72MB
    uint16_t* ab   = xb;                            // alias: xb dead after q GEMM

    cvt2_bf16_kernel<<<2048, 256, 0, stream>>>(x, xb, (H_B * H_SQ * H_D) / 4,
                                               ctx, ctxb, (H_B * H_SK * H_D) / 4);

    wtrans3_kernel<<<dim3(128, 32), dim3(32, 8), 0, stream>>>(Wq, WqT, Wkv, WkvT, Wp, WpT);

    gemm_bt_kernel<0, 64><<<512, 256, 0, stream>>>(xb,   WqT,  bq,  qb, nullptr, H_B * H_SQ, H_D,     H_D);
    gemm_bt_kernel<2, 128><<<1024, 256, 0, stream>>>(ctxb, WkvT, bkv, kb, vTb,   H_B * H_SK, 2 * H_D, H_D);

    attn_kernel<<<H_B * H_NH * (H_SQ / 64), 256, 0, stream>>>(qb, kb, vTb, mask, ab);

    gemm_bt_kernel<1, 64><<<512, 256, 0, stream>>>(ab, WpT, bp, out, nullptr, H_B * H_SQ, H_D, H_D);
}

// Round 14
// 168.840 us; speedup vs baseline: 2.4754x; 1.1700x over previous
//
#include <hip/hip_runtime.h>
#include <stdint.h>

#define H_B  4
#define H_SQ 1024
#define H_SK 2048
#define H_D  1024
#define H_NH 16
#define H_DH 64

typedef __bf16 bf16x8 __attribute__((ext_vector_type(8)));
typedef float  f32x4  __attribute__((ext_vector_type(4)));

__device__ __forceinline__ uint16_t f2bf(float f) {
    union { float f; uint32_t u; } v; v.f = f;
    uint32_t r = v.u + 0x7fffu + ((v.u >> 16) & 1u);
    return (uint16_t)(r >> 16);
}

__device__ __forceinline__ void gload_lds16(const void* g, void* l) {
    __builtin_amdgcn_global_load_lds(
        (const __attribute__((address_space(1))) uint32_t*)g,
        (__attribute__((address_space(3))) uint32_t*)l, 16, 0, 0);
}

#define MFMA_BF16(a, b, c) __builtin_amdgcn_mfma_f32_16x16x32_bf16((a), (b), (c), 0, 0, 0)
#define EXP2(x) __builtin_amdgcn_exp2f(x)

// DPP crosslane (VALU pipe — not DS): xor within 16-lane row groups
template <int CTRL>
__device__ __forceinline__ float dpp_xor(float v) {
    return __builtin_bit_cast(float,
        __builtin_amdgcn_update_dpp(__builtin_bit_cast(int, v),
                                    __builtin_bit_cast(int, v),
                                    CTRL, 0xF, 0xF, false));
}
#define DPP_XOR1 0xB1   // quad_perm(1,0,3,2)
#define DPP_XOR2 0x4E   // quad_perm(2,3,0,1)
#define DPP_XOR4 0x141  // row_half_mirror
#define DPP_XOR8 0x140  // row_mirror

__device__ __forceinline__ float dpp_max16(float v) {
    v = fmaxf(v, dpp_xor<DPP_XOR1>(v));
    v = fmaxf(v, dpp_xor<DPP_XOR2>(v));
    v = fmaxf(v, dpp_xor<DPP_XOR4>(v));
    v = fmaxf(v, dpp_xor<DPP_XOR8>(v));
    return v;
}
__device__ __forceinline__ float dpp_sum16(float v) {
    v += dpp_xor<DPP_XOR1>(v);
    v += dpp_xor<DPP_XOR2>(v);
    v += dpp_xor<DPP_XOR4>(v);
    v += dpp_xor<DPP_XOR8>(v);
    return v;
}

// ---------------- prep: 3 weight transposes + 2 f32->bf16 converts, 1 dispatch --
// blocks 0..4095: wtrans (bx = bid&127 over n: 32 Wq | 64 Wkv | 32 Wp; ky = bid>>7)
// blocks 4096.. : grid-stride cvt over x then ctx (as one index space)
__global__ __launch_bounds__(256) void prep_kernel(
    const float* __restrict__ x, uint16_t* __restrict__ xb,
    const float* __restrict__ ctx, uint16_t* __restrict__ ctxb,
    const float* __restrict__ Wq, uint16_t* __restrict__ WqT,
    const float* __restrict__ Wkv, uint16_t* __restrict__ WkvT,
    const float* __restrict__ Wp, uint16_t* __restrict__ WpT)
{
    __shared__ float tile[32][33];
    int bid = blockIdx.x;
    int t = threadIdx.x;
    if (bid < 4096) {
        int bx = bid & 127, k0 = (bid >> 7) * 32;
        const float* W; uint16_t* WT; int N, n0;
        if (bx < 32)      { W = Wq;  WT = WqT;  N = 1024; n0 = bx * 32; }
        else if (bx < 96) { W = Wkv; WT = WkvT; N = 2048; n0 = (bx - 32) * 32; }
        else              { W = Wp;  WT = WpT;  N = 1024; n0 = (bx - 96) * 32; }
        int tx = t & 31, ty = t >> 5;            // (32,8) reshaped
        #pragma unroll
        for (int i = ty; i < 32; i += 8)
            tile[i][tx] = W[(size_t)(k0 + i) * N + n0 + tx];
        __syncthreads();
        #pragma unroll
        for (int i = ty; i < 32; i += 8)
            WT[(size_t)(n0 + i) * 1024 + k0 + tx] = f2bf(tile[tx][i]);
    } else {
        const int n4a = (H_B * H_SQ * H_D) / 4;
        const int n4b = (H_B * H_SK * H_D) / 4;
        int i = (bid - 4096) * 256 + t;
        int stride = (gridDim.x - 4096) * 256;
        int tot = n4a + n4b;
        for (; i < tot; i += stride) {
            float4 v;
            if (i < n4a) v = ((const float4*)x)[i];
            else         v = ((const float4*)ctx)[i - n4a];
            ushort4 o;
            o.x = f2bf(v.x); o.y = f2bf(v.y); o.z = f2bf(v.z); o.w = f2bf(v.w);
            if (i < n4a) ((ushort4*)xb)[i] = o;
            else         ((ushort4*)ctxb)[i - n4a] = o;
        }
    }
}

// ---------------- GEMM body: C[M][N] = A[M][K] @ BT[N][K]^T + bias, bf16 in -----
// 2-phase double-buffered LDS. BM: 128 (4x4 acc/wave) or 64 (2x4).
// MODE 0: bf16 C. MODE 1: f32 C.
// MODE 2 (kv projection, BM=128): cols < H_D -> kb[row][col] (stride H_D);
//   cols >= H_D -> vT[(b*16+hh)*64+dd][sk] transposed, packed uint2 (fused vtrans).
// wg/nwg passed explicitly so multiple GEMMs can share one dispatch.
template <int MODE, int BM>
__device__ __forceinline__ void gemm_body(
    const uint16_t* __restrict__ A, const uint16_t* __restrict__ BT,
    const float* __restrict__ bias, void* __restrict__ Cv,
    uint16_t* __restrict__ vTb, int M, int N, int K,
    int wg, int nwg, char* smem)
{
    constexpr int MI = BM / 32;              // acc rows of 16x16 frags per wave
    uint16_t (*As)[BM * 32] = (uint16_t (*)[BM * 32])smem;
    uint16_t (*Bs)[128 * 32] = (uint16_t (*)[128 * 32])(smem + 2 * BM * 32 * 2);

    int nbn = N >> 7;
    int cpx = nwg >> 3;                         // nwg divisible by 8 for all our shapes
    wg = (wg & 7) * cpx + (wg >> 3);            // XCD-aware swizzle (bijective)
    int bm = wg / nbn, bn = wg % nbn;

    int t = threadIdx.x;
    int w = t >> 6, l = t & 63;
    int lr = l & 15, lg = l >> 4;
    int wr = (w >> 1) * (BM / 2), wc = (w & 1) * 64;

    const uint16_t* Ab = A + (size_t)bm * BM * K;
    const uint16_t* Bb = BT + (size_t)bn * 128 * K;

    // per-thread staging chunk geometry: chunk c -> row c>>2, 16B piece c&3
    int ca = w * 64 + l;
    int rowa = ca >> 2, kpa = (ca & 3) * 8;
    int cb = 256 + ca;
    int rowb = cb >> 2, kpb = (cb & 3) * 8;
    int offa = ca * 16;          // linear LDS byte offsets (dest = base + lane*16)
    int offb = cb * 16;

    f32x4 acc[MI][4];
    #pragma unroll
    for (int i = 0; i < MI; ++i)
        #pragma unroll
        for (int j = 0; j < 4; ++j) acc[i][j] = {0.f, 0.f, 0.f, 0.f};

    // prologue: stage k0 = 0 into buffer 0 (A: BM*32 tile; 64-row tile = 1 instr)
    gload_lds16(Ab + (size_t)rowa * K + kpa, (char*)As[0] + (offa & ~1023));
    if constexpr (BM == 128)
        gload_lds16(Ab + (size_t)rowb * K + kpb, (char*)As[0] + (offb & ~1023));
    gload_lds16(Bb + (size_t)rowa * K + kpa, (char*)Bs[0] + (offa & ~1023));
    gload_lds16(Bb + (size_t)rowb * K + kpb, (char*)Bs[0] + (offb & ~1023));
    __syncthreads();

    int buf = 0;
    for (int k0 = 0; k0 < K; k0 += 32) {
        if (k0 + 32 < K) {               // stage next K-tile into other buffer
            int kn = k0 + 32;
            gload_lds16(Ab + (size_t)rowa * K + kn + kpa, (char*)As[buf ^ 1] + (offa & ~1023));
            if constexpr (BM == 128)
                gload_lds16(Ab + (size_t)rowb * K + kn + kpb, (char*)As[buf ^ 1] + (offb & ~1023));
            gload_lds16(Bb + (size_t)rowa * K + kn + kpa, (char*)Bs[buf ^ 1] + (offa & ~1023));
            gload_lds16(Bb + (size_t)rowb * K + kn + kpb, (char*)Bs[buf ^ 1] + (offb & ~1023));
        }
        bf16x8 af[MI], bf[4];
        #pragma unroll
        for (int mi = 0; mi < MI; ++mi)
            af[mi] = *(const bf16x8*)&As[buf][(wr + mi * 16 + lr) * 32 + lg * 8];
        #pragma unroll
        for (int ni = 0; ni < 4; ++ni)
            bf[ni] = *(const bf16x8*)&Bs[buf][(wc + ni * 16 + lr) * 32 + lg * 8];
        #pragma unroll
        for (int mi = 0; mi < MI; ++mi)
            #pragma unroll
            for (int ni = 0; ni < 4; ++ni)
                acc[mi][ni] = MFMA_BF16(af[mi], bf[ni], acc[mi][ni]);
        __syncthreads();                 // drains staging vmcnt + read handoff
        buf ^= 1;
    }

    #pragma unroll
    for (int mi = 0; mi < MI; ++mi) {
        #pragma unroll
        for (int ni = 0; ni < 4; ++ni) {
            int col = bn * 128 + wc + ni * 16 + lr;
            float bv = bias[col];
            int row0 = bm * BM + wr + mi * 16 + lg * 4;
            if constexpr (MODE == 2) {
                if (col < H_D) {         // K-half -> kb[row][col], stride H_D
                    uint16_t* kb = (uint16_t*)Cv;
                    #pragma unroll
                    for (int j = 0; j < 4; ++j)
                        kb[(size_t)(row0 + j) * H_D + col] = f2bf(acc[mi][ni][j] + bv);
                } else {                 // V-half -> vT[(b*16+hh)*64+dd][sk], packed
                    int dall = col - H_D;
                    int hh = dall >> 6, dd = dall & 63;
                    int bb = row0 >> 11, sk0 = row0 & 2047;  // 128-tiles don't cross b
                    uint16_t p0 = f2bf(acc[mi][ni][0] + bv);
                    uint16_t p1 = f2bf(acc[mi][ni][1] + bv);
                    uint16_t p2 = f2bf(acc[mi][ni][2] + bv);
                    uint16_t p3 = f2bf(acc[mi][ni][3] + bv);
                    uint32_t lo = (uint32_t)p0 | ((uint32_t)p1 << 16);
                    uint32_t hi = (uint32_t)p2 | ((uint32_t)p3 << 16);
                    *(uint2*)&vTb[((size_t)(bb * 16 + hh) * 64 + dd) * H_SK + sk0] =
                        make_uint2(lo, hi);
                }
            } else {
                #pragma unroll
                for (int j = 0; j < 4; ++j) {
                    float v = acc[mi][ni][j] + bv;
                    if constexpr (MODE == 0)
                        ((uint16_t*)Cv)[(size_t)(row0 + j) * N + col] = f2bf(v);
                    else
                        ((float*)Cv)[(size_t)(row0 + j) * N + col] = v;
                }
            }
        }
    }
}

// q-GEMM (blocks 0..511, <0,64>) + kv-GEMM (blocks 512..1535, <2,128>) fused.
// q sub-grid = 512 ≡ 0 mod 8, so bid%8 == sub-wg%8 -> XCD swizzle stays valid.
__global__ __launch_bounds__(256) void qkv_gemm_kernel(
    const uint16_t* __restrict__ xb, const uint16_t* __restrict__ WqT,
    const float* __restrict__ bq, uint16_t* __restrict__ qb,
    const uint16_t* __restrict__ ctxb, const uint16_t* __restrict__ WkvT,
    const float* __restrict__ bkv, uint16_t* __restrict__ kb,
    uint16_t* __restrict__ vTb)
{
    __shared__ char smem[32768];
    int bid = blockIdx.x;
    if (bid < 512)
        gemm_body<0, 64>(xb, WqT, bq, qb, nullptr, H_B * H_SQ, H_D, H_D,
                         bid, 512, smem);
    else
        gemm_body<2, 128>(ctxb, WkvT, bkv, kb, vTb, H_B * H_SK, 2 * H_D, H_D,
                          bid - 512, 1024, smem);
}

__global__ __launch_bounds__(256) void proj_gemm_kernel(
    const uint16_t* __restrict__ ab, const uint16_t* __restrict__ WpT,
    const float* __restrict__ bp, float* __restrict__ out)
{
    __shared__ char smem[24576];
    gemm_body<1, 64>(ab, WpT, bp, out, nullptr, H_B * H_SQ, H_D, H_D,
                     blockIdx.x, 512, smem);
}

// ---------------- flash attention (r13 verified; lazy defer-max reduce) ---------
// grid 1024; panel-swizzled decode pins each (b,h) panel to one XCD's L2.
// K/V double-buffered via global_load_lds (both-sides XOR swizzle), one
// barrier/tile. p_lds [4][16][64] + row-XOR (LDS 40960 = 4 blocks/CU).
// Defer-max trigger uses LANE-LOCAL max (provably identical trigger:
// any lane exceeding == any group-max exceeding); the 4-hop DPP max
// reduce runs only on the rare rescale path.
__global__ __launch_bounds__(256) void attn_kernel(
    const uint16_t* __restrict__ qb, const uint16_t* __restrict__ kb,
    const uint16_t* __restrict__ vT, const float* __restrict__ mask,
    uint16_t* __restrict__ ab)
{
    __shared__ uint16_t Ks[2][64 * 64];   // [row k][64 d], rows 128B, swizzled cols
    __shared__ uint16_t Vs[2][64 * 64];   // [row d][64 k]
    __shared__ uint16_t p_lds[4][16][64]; // stride 64 + row-XOR -> 8192 B

    int bid = blockIdx.x;
    int xcd = bid & 7;
    int kk = bid >> 3;               // 0..127
    int qt = kk & 15;
    int bh = xcd + 8 * (kk >> 4);    // bijective; panel blocks share bid%8
    int b = bh >> 4, hh = bh & 15;

    int t = threadIdx.x;
    int w = t >> 6, l = t & 63;
    int lr = l & 15, lg = l >> 4;

    // Q fragments straight from global (once per block)
    const uint16_t* qrow = qb + (size_t)(b * H_SQ + qt * 64 + w * 16 + lr) * H_D + hh * H_DH;
    bf16x8 qf0 = *(const bf16x8*)(qrow + lg * 8);
    bf16x8 qf1 = *(const bf16x8*)(qrow + 32 + lg * 8);

    f32x4 acc[4];
    #pragma unroll
    for (int i = 0; i < 4; ++i) acc[i] = {0.f, 0.f, 0.f, 0.f};
    float mrow[4], lsum[4];   // lsum = per-lane PARTIAL (this lane's ni columns)
    #pragma unroll
    for (int j = 0; j < 4; ++j) { mrow[j] = -1e30f; lsum[j] = 0.f; }

    const float SC  = 0.18033688011112042f;   // log2(e)/8
    const float L2E = 1.4426950408889634f;

    // per-lane chunk geometry for staging (16B chunks, 512 per 64x64 tile)
    // chunk c: row r = c>>3, lds col16 cL = c&7, global col16 = cL ^ (r&7)
    int c0 = w * 64 + l;
    int r0 = c0 >> 3,          gc0 = ((c0 & 7) ^ (r0 & 7)) * 8;
    int c1 = 256 + c0;
    int r1 = c1 >> 3,          gc1 = ((c1 & 7) ^ (r1 & 7)) * 8;
    int ldsoff = (w * 64) * 16;               // wave-uniform byte offset, instr 0
    const uint16_t* kbase = kb + (size_t)b * H_SK * H_D + hh * H_DH;
    const uint16_t* vbase = vT + (size_t)bh * H_DH * H_SK;

    // p_lds XOR keys
    int xkbase = (lg & 1) << 5;               // write key base; | (j<<3) per j
    int rdkey  = (lr & 7) << 3;               // read key for row lr

    // prologue: stage tile 0, preload mask(0) premultiplied by log2(e)
    float msk_nxt[4];
    {
        gload_lds16(kbase + (size_t)r0 * H_D + gc0, (char*)Ks[0] + ldsoff);
        gload_lds16(kbase + (size_t)r1 * H_D + gc1, (char*)Ks[0] + ldsoff + 4096);
        gload_lds16(vbase + (size_t)r0 * H_SK + gc0, (char*)Vs[0] + ldsoff);
        gload_lds16(vbase + (size_t)r1 * H_SK + gc1, (char*)Vs[0] + ldsoff + 4096);
        #pragma unroll
        for (int ni = 0; ni < 4; ++ni) msk_nxt[ni] = mask[b * H_SK + ni * 16 + lr] * L2E;
    }
    __syncthreads();   // implicit vmcnt(0): tile 0 landed

    int cur = 0;
    for (int kt = 0; kt < H_SK / 64; ++kt) {
        float msk_cur[4];
        #pragma unroll
        for (int ni = 0; ni < 4; ++ni) msk_cur[ni] = msk_nxt[ni];

        if (kt + 1 < H_SK / 64) {        // stage next tile into other buffer
            int sk1 = (kt + 1) * 64;
            int nxt = cur ^ 1;
            gload_lds16(kbase + (size_t)(sk1 + r0) * H_D + gc0, (char*)Ks[nxt] + ldsoff);
            gload_lds16(kbase + (size_t)(sk1 + r1) * H_D + gc1, (char*)Ks[nxt] + ldsoff + 4096);
            // V^T rows are d (stride H_SK); k-offset sk1 adds AFTER row*stride
            gload_lds16(vbase + (size_t)r0 * H_SK + sk1 + gc0, (char*)Vs[nxt] + ldsoff);
            gload_lds16(vbase + (size_t)r1 * H_SK + sk1 + gc1, (char*)Vs[nxt] + ldsoff + 4096);
            #pragma unroll
            for (int ni = 0; ni < 4; ++ni) msk_nxt[ni] = mask[b * H_SK + sk1 + ni * 16 + lr] * L2E;
        }

        const uint16_t* Kb = Ks[cur];
        const uint16_t* Vb = Vs[cur];
        int sw = (lg ^ (lr & 7)) * 8;    // swizzled col (elements) for frag reads

        // S = Q K^T
        f32x4 s[4];
        #pragma unroll
        for (int ni = 0; ni < 4; ++ni) s[ni] = {0.f, 0.f, 0.f, 0.f};
        #pragma unroll
        for (int ni = 0; ni < 4; ++ni) {
            bf16x8 kf0 = *(const bf16x8*)&Kb[(ni * 16 + lr) * 64 + sw];
            bf16x8 kf1 = *(const bf16x8*)&Kb[(ni * 16 + lr) * 64 + (sw ^ 32)];
            s[ni] = MFMA_BF16(qf0, kf0, s[ni]);
            s[ni] = MFMA_BF16(qf1, kf1, s[ni]);
        }

        // online softmax, exp2 domain — lane-local defer-max test; DPP reduce
        // only inside the (rare) rescale branch
        float lg2[4][4], mxl[4];
        #pragma unroll
        for (int j = 0; j < 4; ++j) {
            float a0 = fmaf(s[0][j], SC, msk_cur[0]);
            float a1 = fmaf(s[1][j], SC, msk_cur[1]);
            float a2 = fmaf(s[2][j], SC, msk_cur[2]);
            float a3 = fmaf(s[3][j], SC, msk_cur[3]);
            lg2[0][j] = a0; lg2[1][j] = a1; lg2[2][j] = a2; lg2[3][j] = a3;
            mxl[j] = fmaxf(fmaxf(a0, a1), fmaxf(a2, a3));
        }
        int grow = 0;
        #pragma unroll
        for (int j = 0; j < 4; ++j)
            grow |= (mxl[j] > mrow[j] + 8.0f) ? 1 : 0;
        if (__any(grow)) {
            #pragma unroll
            for (int j = 0; j < 4; ++j) {
                float mx = dpp_max16(mxl[j]);
                float nm = fmaxf(mrow[j], mx);
                float alpha = EXP2(mrow[j] - nm);
                mrow[j] = nm;
                lsum[j] *= alpha;          // partial: linear in alpha, stays valid
                #pragma unroll
                for (int ni = 0; ni < 4; ++ni) acc[ni][j] *= alpha;
            }
        }
        #pragma unroll
        for (int ni = 0; ni < 4; ++ni)
            #pragma unroll
            for (int j = 0; j < 4; ++j) {
                float p = EXP2(lg2[ni][j] - mrow[j]);
                lsum[j] += p;              // per-lane partial; no cross-lane here
                uint32_t pk;
                asm("v_cvt_pk_bf16_f32 %0, %1, %2" : "=v"(pk) : "v"(p), "v"(p));
                p_lds[w][lg * 4 + j][(ni * 16 + lr) ^ (xkbase | (j << 3))] = (uint16_t)pk;
            }

        // O += P V  (p_lds wave-private; compiler inserts lgkm waits)
        int pc0 = (lg * 8) ^ rdkey;
        bf16x8 pf0 = *(const bf16x8*)&p_lds[w][lr][pc0];
        bf16x8 pf1 = *(const bf16x8*)&p_lds[w][lr][pc0 ^ 32];
        #pragma unroll
        for (int ni = 0; ni < 4; ++ni) {
            bf16x8 vf0 = *(const bf16x8*)&Vb[(ni * 16 + lr) * 64 + sw];
            bf16x8 vf1 = *(const bf16x8*)&Vb[(ni * 16 + lr) * 64 + (sw ^ 32)];
            acc[ni] = MFMA_BF16(pf0, vf0, acc[ni]);
            acc[ni] = MFMA_BF16(pf1, vf1, acc[ni]);
        }

        __syncthreads();   // drains this iter's gloads (vmcnt 0) + protects buffers
        cur ^= 1;
    }

    // single cross-lane sum reduce at the end (16-lane row groups)
    float inv[4];
    #pragma unroll
    for (int j = 0; j < 4; ++j) inv[j] = 1.0f / dpp_sum16(lsum[j]);
    #pragma unroll
    for (int ni = 0; ni < 4; ++ni)
        #pragma unroll
        for (int j = 0; j < 4; ++j) {
            int row = qt * 64 + w * 16 + lg * 4 + j;
            int col = hh * H_DH + ni * 16 + lr;
            ab[(size_t)(b * H_SQ + row) * H_D + col] = f2bf(acc[ni][j] * inv[j]);
        }
}

// ---------------- host ----------------------------------------------------------
extern "C" void kernel_launch(void* const* d_in, const int* in_sizes, int n_in,
                              void* d_out, int out_size, void* d_ws, size_t ws_size,
                              hipStream_t stream) {
    const float* x    = (const float*)d_in[0];
    const float* ctx  = (const float*)d_in[1];
    const float* mask = (const float*)d_in[2];
    const float* Wq   = (const float*)d_in[3];
    const float* bq   = (const float*)d_in[4];
    const float* Wkv  = (const float*)d_in[5];
    const float* bkv  = (const float*)d_in[6];
    const float* Wp   = (const float*)d_in[7];
    const float* bp   = (const float*)d_in[8];
    float* out = (float*)d_out;

    char* ws = (char*)d_ws;
    uint16_t* xb   = (uint16_t*)(ws + 0);          //  8MB (reused as ab after q GEMM)
    uint16_t* ctxb = (uint16_t*)(ws + 8388608);    // 16MB
    uint16_t* vTb  = (uint16_t*)(ws + 25165824);   // 16MB (written BY kv GEMM -> no alias with ctxb)
    uint16_t* WqT  = (uint16_t*)(ws + 41943040);   //  2MB
    uint16_t* WkvT = (uint16_t*)(ws + 44040192);   //  4MB
    uint16_t* WpT  = (uint16_t*)(ws + 48234496);   //  2MB
    uint16_t* qb   = (uint16_t*)(ws + 50331648);   //  8MB
    uint16_t* kb   = (uint16_t*)(ws + 58720256);   // 16MB -> total 72MB
    uint16_t* ab   = xb;                            // alias: xb dead after q GEMM

    prep_kernel<<<7168, 256, 0, stream>>>(x, xb, ctx, ctxb, Wq, WqT, Wkv, WkvT, Wp, WpT);

    qkv_gemm_kernel<<<1536, 256, 0, stream>>>(xb, WqT, bq, qb, ctxb, WkvT, bkv, kb, vTb);

    attn_kernel<<<H_B * H_NH * (H_SQ / 64), 256, 0, stream>>>(qb, kb, vTb, mask, ab);

    proj_gemm_kernel<<<512, 256, 0, stream>>>(ab, WpT, bp, out);
}